// Round 2
// baseline (848.129 us; speedup 1.0000x reference)
//
#include <hip/hip_runtime.h>
#include <math.h>

// Problem constants (from reference setup_inputs)
#define B_SZ   16
#define CIN    64
#define T_LEN  8192
#define N_ST   256
#define OCH    64
#define CHUNK  128            // L: timesteps per scan chunk
#define NCHUNK (T_LEN/CHUNK)  // J = 64
#define TS     32             // t sub-tile within a chunk

// Workspace layout (floats):
//  [0]       A_d       : 256
//  [256]     A_L       : 256          (A_d^CHUNK)
//  [512]     B_d       : 64*256      ([c][n])
//  [16896]   e         : J*B*N = 262144   ([j][b][n])
//  [279040]  sinit     : 262144           ([j][b][n])
//  [541184]  y         : B*T*O = 8388608  ([b][t][o])  -> total ~34.1 MiB
#define WS_AD    0
#define WS_AL    256
#define WS_BD    512
#define WS_E     16896
#define WS_SINIT 279040
#define WS_Y     541184

// ---------------- prep: discretization ----------------
__global__ __launch_bounds__(256) void k_prep(const float* __restrict__ raw_lambda,
                                              const float* __restrict__ B_c,
                                              float* __restrict__ ws) {
    int n = threadIdx.x;
    float rl = raw_lambda[n];
    float sp = (rl > 20.f) ? rl : log1pf(expf(rl));   // softplus
    float lam = -sp;
    float A = expf(lam);                               // DT = 1
    float factor = (fabsf(lam) > 1e-6f) ? (A - 1.f) / lam : 1.0f;
    ws[WS_AD + n] = A;
    ws[WS_AL + n] = expf(lam * (float)CHUNK);
    float* Bd = ws + WS_BD;
    for (int c = 0; c < CIN; ++c)
        Bd[c * N_ST + n] = B_c[c * N_ST + n] * factor;
}

// ---------------- pass1: per-chunk local carry e ----------------
// e[j][b][n] = sum_{k<CHUNK} A^(CHUNK-1-k) * v[t0+k][b][n],  v = u . B_d
__global__ __launch_bounds__(256) void k_pass1(const float* __restrict__ u,
                                               const float* __restrict__ ws,
                                               float* __restrict__ e_out) {
    const int j = blockIdx.x;
    const int b = blockIdx.y;
    const int n = threadIdx.x;
    __shared__ float u_lds[TS][68];   // transposed tile [t][c], pad 68 (row 272B, 16B-aligned)

    float bd[CIN];
    const float* Bd = ws + WS_BD;
#pragma unroll
    for (int c = 0; c < CIN; ++c) bd[c] = Bd[c * N_ST + n];
    const float A = ws[WS_AD + n];

    float s = 0.f;
    const int t0 = j * CHUNK;
    const float* ub = u + (size_t)b * CIN * T_LEN;

    for (int ts = 0; ts < CHUNK / TS; ++ts) {
        __syncthreads();
        {   // stage u[b][c][t0+ts*TS .. +TS) transposed into LDS
            int c = threadIdx.x >> 2;
            int k = threadIdx.x & 3;
            const float* src = ub + (size_t)c * T_LEN + t0 + ts * TS + k * 8;
            float4 v0 = *(const float4*)src;
            float4 v1 = *(const float4*)(src + 4);
            int cb = k * 8;
            u_lds[cb + 0][c] = v0.x; u_lds[cb + 1][c] = v0.y;
            u_lds[cb + 2][c] = v0.z; u_lds[cb + 3][c] = v0.w;
            u_lds[cb + 4][c] = v1.x; u_lds[cb + 5][c] = v1.y;
            u_lds[cb + 6][c] = v1.z; u_lds[cb + 7][c] = v1.w;
        }
        __syncthreads();
#pragma unroll
        for (int t = 0; t < TS; ++t) {
            const float4* ur = (const float4*)&u_lds[t][0];   // broadcast row -> no conflicts
            float p0 = 0.f, p1 = 0.f, p2 = 0.f, p3 = 0.f;
#pragma unroll
            for (int cc = 0; cc < 16; cc += 4) {
                float4 a0 = ur[cc + 0], a1 = ur[cc + 1], a2 = ur[cc + 2], a3 = ur[cc + 3];
                p0 += a0.x * bd[4*cc+0]  + a0.y * bd[4*cc+1]  + a0.z * bd[4*cc+2]  + a0.w * bd[4*cc+3];
                p1 += a1.x * bd[4*cc+4]  + a1.y * bd[4*cc+5]  + a1.z * bd[4*cc+6]  + a1.w * bd[4*cc+7];
                p2 += a2.x * bd[4*cc+8]  + a2.y * bd[4*cc+9]  + a2.z * bd[4*cc+10] + a2.w * bd[4*cc+11];
                p3 += a3.x * bd[4*cc+12] + a3.y * bd[4*cc+13] + a3.z * bd[4*cc+14] + a3.w * bd[4*cc+15];
            }
            float v = (p0 + p1) + (p2 + p3);
            s = s * A + v;
        }
    }
    e_out[((size_t)j * B_SZ + b) * N_ST + n] = s;
}

// ---------------- pass2: sequential chunk-prefix combine ----------------
__global__ __launch_bounds__(256) void k_pass2(float* __restrict__ ws) {
    const int b = blockIdx.x;
    const int n = threadIdx.x;
    const float AL = ws[WS_AL + n];
    const float* e = ws + WS_E;
    float* si = ws + WS_SINIT;
    float s = 0.f;
#pragma unroll 8
    for (int j = 0; j < NCHUNK; ++j) {
        size_t idx = ((size_t)j * B_SZ + b) * N_ST + n;
        si[idx] = s;                 // state BEFORE chunk j
        s = s * AL + e[idx];
    }
}

// ---------------- pass3: scan + y = S*C + LN + SiLU ----------------
__global__ __launch_bounds__(256) void k_pass3(const float* __restrict__ u,
                                               const float* __restrict__ C,
                                               const float* __restrict__ ln_w,
                                               const float* __restrict__ ln_b,
                                               const float* __restrict__ ws,
                                               float* __restrict__ y_out) {
    const int j = blockIdx.x;
    const int b = blockIdx.y;
    const int tid = threadIdx.x;
    const int n = tid;

    __shared__ float u_lds[TS][68];       //  8.5 KB
    __shared__ float S_lds[TS][257];      // 32.1 KB  [t][n], pad 257 -> conflict-free column reads
    __shared__ float C_lds[64][64];       // 16.0 KB  quarter of C, restaged per quarter
    __shared__ float red[TS][8][2];       //  2.0 KB     => 58.6 KB static total (< 64 KB)

    float bd[CIN];
    const float* Bd = ws + WS_BD;
#pragma unroll
    for (int c = 0; c < CIN; ++c) bd[c] = Bd[c * N_ST + n];
    const float A = ws[WS_AD + n];
    float s = ws[WS_SINIT + ((size_t)j * B_SZ + b) * N_ST + n];

    // y-phase identity
    const int ty = tid & 31;
    const int og = tid >> 5;   // 0..7, owns output channels og*8..og*8+7
    float lw[8], lb[8];
#pragma unroll
    for (int q = 0; q < 8; ++q) { lw[q] = ln_w[og * 8 + q]; lb[q] = ln_b[og * 8 + q]; }

    const int t0 = j * CHUNK;
    const float* ub = u + (size_t)b * CIN * T_LEN;

    for (int ts = 0; ts < CHUNK / TS; ++ts) {
        __syncthreads();
        {   // stage u transposed
            int c = tid >> 2;
            int k = tid & 3;
            const float* src = ub + (size_t)c * T_LEN + t0 + ts * TS + k * 8;
            float4 v0 = *(const float4*)src;
            float4 v1 = *(const float4*)(src + 4);
            int cb = k * 8;
            u_lds[cb + 0][c] = v0.x; u_lds[cb + 1][c] = v0.y;
            u_lds[cb + 2][c] = v0.z; u_lds[cb + 3][c] = v0.w;
            u_lds[cb + 4][c] = v1.x; u_lds[cb + 5][c] = v1.y;
            u_lds[cb + 6][c] = v1.z; u_lds[cb + 7][c] = v1.w;
        }
        __syncthreads();
        // local scan, deposit states to S_lds
#pragma unroll
        for (int t = 0; t < TS; ++t) {
            const float4* ur = (const float4*)&u_lds[t][0];
            float p0 = 0.f, p1 = 0.f, p2 = 0.f, p3 = 0.f;
#pragma unroll
            for (int cc = 0; cc < 16; cc += 4) {
                float4 a0 = ur[cc + 0], a1 = ur[cc + 1], a2 = ur[cc + 2], a3 = ur[cc + 3];
                p0 += a0.x * bd[4*cc+0]  + a0.y * bd[4*cc+1]  + a0.z * bd[4*cc+2]  + a0.w * bd[4*cc+3];
                p1 += a1.x * bd[4*cc+4]  + a1.y * bd[4*cc+5]  + a1.z * bd[4*cc+6]  + a1.w * bd[4*cc+7];
                p2 += a2.x * bd[4*cc+8]  + a2.y * bd[4*cc+9]  + a2.z * bd[4*cc+10] + a2.w * bd[4*cc+11];
                p3 += a3.x * bd[4*cc+12] + a3.y * bd[4*cc+13] + a3.z * bd[4*cc+14] + a3.w * bd[4*cc+15];
            }
            float v = (p0 + p1) + (p2 + p3);
            s = s * A + v;
            S_lds[t][n] = s;
        }
        __syncthreads();

        // y[t][o] = sum_n S[t][n] * C[n][o], accumulated in regs; C staged in 64-row quarters
        float acc[8];
#pragma unroll
        for (int q = 0; q < 8; ++q) acc[q] = 0.f;

        for (int quad = 0; quad < 4; ++quad) {
            {   // stage C[quad*64 .. +64)[0..64): 256 thr x 16 floats
                int r = tid >> 2;
                int kk = tid & 3;
                const float4* src = (const float4*)(C + ((size_t)(quad * 64 + r)) * OCH + kk * 16);
                float4* dst = (float4*)&C_lds[r][kk * 16];
#pragma unroll
                for (int q = 0; q < 4; ++q) dst[q] = src[q];
            }
            __syncthreads();
#pragma unroll 4
            for (int nl = 0; nl < 64; ++nl) {
                float sv = S_lds[ty][quad * 64 + nl];          // stride-257 column: conflict-free
                float4 c0 = *(const float4*)&C_lds[nl][og * 8]; // broadcast within og-group
                float4 c1 = *(const float4*)&C_lds[nl][og * 8 + 4];
                acc[0] += sv * c0.x; acc[1] += sv * c0.y;
                acc[2] += sv * c0.z; acc[3] += sv * c0.w;
                acc[4] += sv * c1.x; acc[5] += sv * c1.y;
                acc[6] += sv * c1.z; acc[7] += sv * c1.w;
            }
            __syncthreads();
        }

        // LayerNorm over 64 channels (+ SiLU), then store y
        {
            float s1 = 0.f, s2 = 0.f;
#pragma unroll
            for (int q = 0; q < 8; ++q) { s1 += acc[q]; s2 += acc[q] * acc[q]; }
            red[ty][og][0] = s1;
            red[ty][og][1] = s2;
            __syncthreads();
            float m1 = 0.f, m2 = 0.f;
#pragma unroll
            for (int g = 0; g < 8; ++g) { m1 += red[ty][g][0]; m2 += red[ty][g][1]; }
            float mu = m1 * (1.f / 64.f);
            float var = m2 * (1.f / 64.f) - mu * mu;
            float rs = rsqrtf(var + 1e-5f);
            float yo[8];
#pragma unroll
            for (int q = 0; q < 8; ++q) {
                float yn = (acc[q] - mu) * rs * lw[q] + lb[q];
                yo[q] = yn / (1.f + expf(-yn));        // SiLU
            }
            float* yrow = y_out + (((size_t)b * T_LEN) + (t0 + ts * TS + ty)) * OCH + og * 8;
            *(float4*)yrow       = make_float4(yo[0], yo[1], yo[2], yo[3]);
            *(float4*)(yrow + 4) = make_float4(yo[4], yo[5], yo[6], yo[7]);
        }
    }
}

// ---------------- conv: upsample (channel-mix) + pointwise conv ----------------
// Torch expand+reshape semantics: x[b][2c][t] = y[b][c][t/2], x[b][2c+1][t] = y[b][c][T/2 + t/2]
// => out[b][o][2tau(+1)] = sum_c w[o][2c]*y_ws[b][tau][c] + w[o][2c+1]*y_ws[b][T/2+tau][c] + cb[o]
__global__ __launch_bounds__(256) void k_conv(const float* __restrict__ y,
                                              const float* __restrict__ conv_w,
                                              const float* __restrict__ conv_b,
                                              float* __restrict__ out) {
    const int tb = blockIdx.x;     // tau chunk (32 taus)
    const int b  = blockIdx.y;
    const int tid = threadIdx.x;

    __shared__ float ylo[32][64];  //  8 KB
    __shared__ float yhi[32][64];  //  8 KB
    __shared__ float WT[128][64];  // 32 KB : WT[c2][o] = conv_w[o][c2]   => 48 KB total

    {   // stage W transposed: 256 thr x 32 floats
        int o = tid >> 2, kk = tid & 3;
        const float4* src = (const float4*)(conv_w + (size_t)o * 128 + kk * 32);
#pragma unroll
        for (int q = 0; q < 8; ++q) {
            float4 w4 = src[q];
            int c2 = kk * 32 + q * 4;
            WT[c2 + 0][o] = w4.x; WT[c2 + 1][o] = w4.y;
            WT[c2 + 2][o] = w4.z; WT[c2 + 3][o] = w4.w;
        }
    }
    const int tau0 = tb * 32;
    {   // stage y rows: r in [0,32), each thread 8 floats per buffer
        int r = tid >> 3, kk = tid & 7;
        const float4* sl = (const float4*)(y + (((size_t)b * T_LEN) + tau0 + r) * OCH + kk * 8);
        const float4* sh = (const float4*)(y + (((size_t)b * T_LEN) + T_LEN / 2 + tau0 + r) * OCH + kk * 8);
        float4* dl = (float4*)&ylo[r][kk * 8];
        float4* dh = (float4*)&yhi[r][kk * 8];
        dl[0] = sl[0]; dl[1] = sl[1];
        dh[0] = sh[0]; dh[1] = sh[1];
    }
    __syncthreads();

    const int o  = tid & 63;
    const int tg = tid >> 6;       // 4 groups x 8 taus
    const float cb = conv_b[o];
    float* ob = out + ((size_t)b * OCH + o) * T_LEN;

    for (int i = 0; i < 8; ++i) {
        int tl = tg * 8 + i;
        float a0 = 0.f, a1 = 0.f, a2 = 0.f, a3 = 0.f;
#pragma unroll
        for (int c = 0; c < 64; c += 2) {
            a0 += WT[2*c    ][o] * ylo[tl][c];
            a1 += WT[2*c + 1][o] * yhi[tl][c];
            a2 += WT[2*c + 2][o] * ylo[tl][c + 1];
            a3 += WT[2*c + 3][o] * yhi[tl][c + 1];
        }
        float r = (a0 + a1) + (a2 + a3) + cb;
        int t2 = 2 * (tau0 + tl);
        float2 rr; rr.x = r; rr.y = r;
        *(float2*)&ob[t2] = rr;    // out[...,2tau] == out[...,2tau+1]
    }
}

extern "C" void kernel_launch(void* const* d_in, const int* in_sizes, int n_in,
                              void* d_out, int out_size, void* d_ws, size_t ws_size,
                              hipStream_t stream) {
    const float* u          = (const float*)d_in[0];
    const float* raw_lambda = (const float*)d_in[1];
    const float* B_c        = (const float*)d_in[2];
    const float* C          = (const float*)d_in[3];
    const float* ln_w       = (const float*)d_in[4];
    const float* ln_b       = (const float*)d_in[5];
    const float* conv_w     = (const float*)d_in[6];
    const float* conv_b     = (const float*)d_in[7];
    float* out = (float*)d_out;
    float* ws  = (float*)d_ws;
    (void)in_sizes; (void)n_in; (void)out_size; (void)ws_size;

    k_prep <<<1, 256, 0, stream>>>(raw_lambda, B_c, ws);
    k_pass1<<<dim3(NCHUNK, B_SZ), 256, 0, stream>>>(u, ws, ws + WS_E);
    k_pass2<<<B_SZ, 256, 0, stream>>>(ws);
    k_pass3<<<dim3(NCHUNK, B_SZ), 256, 0, stream>>>(u, C, ln_w, ln_b, ws, ws + WS_Y);
    k_conv <<<dim3(T_LEN / 2 / 32, B_SZ), 256, 0, stream>>>(ws + WS_Y, conv_w, conv_b, out);
}

// Round 5
// 351.715 us; speedup vs baseline: 2.4114x; 2.4114x over previous
//
#include <hip/hip_runtime.h>
#include <math.h>

// Problem constants
#define B_SZ   16
#define CIN    64
#define T_LEN  8192
#define N_ST   256
#define OCH    64
#define CHUNK  128
#define NCHUNK (T_LEN/CHUNK)   // 64

// Workspace float offsets (total 8,667,904 floats = 34.7 MB; proven ws >= 35.7 MB)
#define WS_AD    0            // A_d            (256)
#define WS_AL    256          // A_d^128        (256)
#define WS_A32   512          // A_d^32         (256)
#define WS_BD    768          // B_d [c][n]     (64*256)
#define WS_ES    17152        // e -> sinit in-place [j][b][n] (64*16*256)
#define WS_Y     279296       // y [b][t][o]    (16*8192*64)

#define FMA4(a, s, b) { (a).x = fmaf((s),(b).x,(a).x); (a).y = fmaf((s),(b).y,(a).y); \
                        (a).z = fmaf((s),(b).z,(a).z); (a).w = fmaf((s),(b).w,(a).w); }

__device__ __forceinline__ unsigned int rne16(float x) {
    unsigned int u = __float_as_uint(x);
    return u + 0x7fffu + ((u >> 16) & 1u);      // RNE to bf16 (result in high 16 bits)
}
__device__ __forceinline__ unsigned int pack2(float even, float odd) {
    return (rne16(even) >> 16) | (rne16(odd) & 0xffff0000u);
}
__device__ __forceinline__ float bf_lo(unsigned int w) { return __uint_as_float(w << 16); }
__device__ __forceinline__ float bf_hi(unsigned int w) { return __uint_as_float(w & 0xffff0000u); }

// ---------------- prep: discretization ----------------
__global__ __launch_bounds__(256) void k_prep(const float* __restrict__ raw_lambda,
                                              const float* __restrict__ B_c,
                                              float* __restrict__ ws) {
    int n = threadIdx.x;
    float rl = raw_lambda[n];
    float sp = (rl > 20.f) ? rl : log1pf(expf(rl));   // softplus
    float lam = -sp;
    float A = expf(lam);                               // DT = 1
    float factor = (fabsf(lam) > 1e-6f) ? (A - 1.f) / lam : 1.0f;
    ws[WS_AD + n]  = A;
    ws[WS_AL + n]  = expf(lam * (float)CHUNK);
    ws[WS_A32 + n] = expf(lam * 32.f);
    float* Bd = ws + WS_BD;
    for (int c = 0; c < CIN; ++c)
        Bd[c * N_ST + n] = B_c[c * N_ST + n] * factor;
}

// ---------------- pass1: v = u.B_d (bf16-packed to v_out) + chunk carry e ----------------
// thread (tg=tid>>6, ns=tid&63): owns t = tg*32..+32, n = ns*4..+4
__global__ __launch_bounds__(256, 1) void k_pass1v(const float* __restrict__ u,
                                                   const float* __restrict__ ws,
                                                   float* __restrict__ e_out,
                                                   unsigned int* __restrict__ v_out,
                                                   int b_off) {
    const int j  = blockIdx.x;
    const int bb = blockIdx.y;          // 0..7 within phase
    const int b  = bb + b_off;          // global batch
    const int tid = threadIdx.x;
    const int tg = tid >> 6;
    const int n0 = (tid & 63) * 4;

    __shared__ float u_lds[64 * 132];    // 33.8 KB  [c][t], stride 132
    __shared__ float part[4 * 256];      //  4 KB

    {   // stage u chunk [64c][128t], coalesced 128B runs per c
        const float* ub = u + (size_t)b * CIN * T_LEN + j * CHUNK;
#pragma unroll
        for (int p = 0; p < 2; ++p) {
            int c = p * 32 + (tid >> 3), k = tid & 7;
#pragma unroll
            for (int i = 0; i < 4; ++i)
                *(float4*)&u_lds[c * 132 + k * 16 + i * 4] =
                    *(const float4*)&ub[(size_t)c * T_LEN + k * 16 + i * 4];
        }
    }
    __syncthreads();

    float4 acc[32];                      // acc[i] = v[t=tg*32+i][n0..n0+4)
#pragma unroll
    for (int i = 0; i < 32; ++i) acc[i] = make_float4(0.f, 0.f, 0.f, 0.f);

    const float* Bd = ws + WS_BD;        // read direct from L2 (contiguous 1KB/wave/c)
#pragma unroll 2
    for (int c = 0; c < 64; ++c) {
        float4 bd4 = *(const float4*)&Bd[c * N_ST + n0];
        const float* ur = &u_lds[c * 132 + tg * 32];
#pragma unroll
        for (int q = 0; q < 8; ++q) {
            float4 uq = *(const float4*)&ur[q * 4];   // wave-broadcast
            FMA4(acc[q * 4 + 0], uq.x, bd4);
            FMA4(acc[q * 4 + 1], uq.y, bd4);
            FMA4(acc[q * 4 + 2], uq.z, bd4);
            FMA4(acc[q * 4 + 3], uq.w, bd4);
        }
    }

    // ---- chunk carry: p = sum_i A^(31-i) v[i]; combine 4 t-slices with A^32 ----
    {
        float4 a4 = *(const float4*)&ws[WS_AD + n0];
        float4 p = make_float4(0.f, 0.f, 0.f, 0.f);
#pragma unroll
        for (int i = 0; i < 32; ++i) {
            p.x = fmaf(p.x, a4.x, acc[i].x);
            p.y = fmaf(p.y, a4.y, acc[i].y);
            p.z = fmaf(p.z, a4.z, acc[i].z);
            p.w = fmaf(p.w, a4.w, acc[i].w);
        }
        *(float4*)&part[tg * 256 + n0] = p;
    }
    __syncthreads();
    if (tg == 0) {
        float4 A32 = *(const float4*)&ws[WS_A32 + n0];
        float4 e  = *(const float4*)&part[0 * 256 + n0];
        float4 p1 = *(const float4*)&part[1 * 256 + n0];
        float4 p2 = *(const float4*)&part[2 * 256 + n0];
        float4 p3 = *(const float4*)&part[3 * 256 + n0];
        e.x = fmaf(e.x, A32.x, p1.x); e.y = fmaf(e.y, A32.y, p1.y);
        e.z = fmaf(e.z, A32.z, p1.z); e.w = fmaf(e.w, A32.w, p1.w);
        e.x = fmaf(e.x, A32.x, p2.x); e.y = fmaf(e.y, A32.y, p2.y);
        e.z = fmaf(e.z, A32.z, p2.z); e.w = fmaf(e.w, A32.w, p2.w);
        e.x = fmaf(e.x, A32.x, p3.x); e.y = fmaf(e.y, A32.y, p3.y);
        e.z = fmaf(e.z, A32.z, p3.z); e.w = fmaf(e.w, A32.w, p3.w);
        *(float4*)&e_out[((size_t)j * B_SZ + b) * N_ST + n0] = e;
    }

    // ---- store v as bf16 pairs: v[bb][t2][n] uint, coalesced ----
    {
        size_t base = (((size_t)bb * 4096) + (size_t)j * 64 + tg * 16) * 256 + n0;
#pragma unroll
        for (int m = 0; m < 16; ++m) {
            uint4 w;
            w.x = pack2(acc[2 * m].x, acc[2 * m + 1].x);
            w.y = pack2(acc[2 * m].y, acc[2 * m + 1].y);
            w.z = pack2(acc[2 * m].z, acc[2 * m + 1].z);
            w.w = pack2(acc[2 * m].w, acc[2 * m + 1].w);
            *(uint4*)&v_out[base + (size_t)m * 256] = w;
        }
    }
}

// ---------------- pass2: chunk-prefix combine, e -> sinit in place ----------------
__global__ __launch_bounds__(256) void k_pass2(float* __restrict__ ws, int b_off) {
    const int b = blockIdx.x + b_off;
    const int n = threadIdx.x;
    const float AL = ws[WS_AL + n];
    float* es = ws + WS_ES;
    float ev[NCHUNK];
#pragma unroll
    for (int j = 0; j < NCHUNK; ++j)     // all loads issued up-front (independent)
        ev[j] = es[((size_t)j * B_SZ + b) * N_ST + n];
    float s = 0.f;
#pragma unroll
    for (int j = 0; j < NCHUNK; ++j) {
        es[((size_t)j * B_SZ + b) * N_ST + n] = s;   // sinit: state BEFORE chunk j
        s = s * AL + ev[j];
    }
}

// ---------------- pass3: scan (v from global) + S.C + LN + SiLU ----------------
// scan: thread = n. projection: thread (og=tid&15 -> 4 o's, tg=tid>>4 -> 4 t's)
// S_lds dense [256][64] with 16B-unit XOR swizzle: col4' = col4 ^ (row & 15)
__global__ __launch_bounds__(256, 1) void k_pass3v(const float* __restrict__ C,
                                                   const float* __restrict__ ln_w,
                                                   const float* __restrict__ ln_b,
                                                   const float* __restrict__ ws,
                                                   const unsigned int* __restrict__ v_in,
                                                   float* __restrict__ y_out,
                                                   int b_off) {
    const int j  = blockIdx.x;
    const int bb = blockIdx.y;
    const int b  = bb + b_off;
    const int tid = threadIdx.x;

    __shared__ float S_lds[256 * 64];    // 64 KB [n][t] swizzled
    __shared__ float C_lds[256 * 64];    // 64 KB [n][o] flat   => 128 KB total

    {   // stage C, coalesced flat copy
#pragma unroll
        for (int g = 0; g < 16; ++g)
            ((float4*)C_lds)[g * 256 + tid] = ((const float4*)C)[g * 256 + tid];
    }

    const int n = tid;
    const float A = ws[WS_AD + n];
    float s = ws[WS_ES + ((size_t)j * B_SZ + b) * N_ST + n];

    const int og = tid & 15;             // o = og*4..+4
    const int tg = tid >> 4;             // t_loc = tg*4..+4 within 64-t half
    float4 lw4 = *(const float4*)&ln_w[og * 4];
    float4 lb4 = *(const float4*)&ln_b[og * 4];

    for (int half = 0; half < 2; ++half) {
        if (half) __syncthreads();       // prev projection done before S overwrite

        // ---- scan 64 t, v from global (L2/L3-resident), deposit S[n][t] swizzled ----
        {
            size_t vb = (((size_t)bb * 4096) + (size_t)j * 64 + half * 32) * 256 + n;
            unsigned int vv[32];
#pragma unroll
            for (int i = 0; i < 32; ++i) vv[i] = v_in[vb + (size_t)i * 256];
#pragma unroll
            for (int q = 0; q < 16; ++q) {
                unsigned int w0 = vv[2 * q], w1 = vv[2 * q + 1];
                float4 s4;
                s = fmaf(s, A, bf_lo(w0)); s4.x = s;
                s = fmaf(s, A, bf_hi(w0)); s4.y = s;
                s = fmaf(s, A, bf_lo(w1)); s4.z = s;
                s = fmaf(s, A, bf_hi(w1)); s4.w = s;
                *(float4*)&S_lds[n * 64 + (q ^ (n & 15)) * 4] = s4;
            }
        }
        __syncthreads();

        // ---- projection: acc[ti][4o], 2 LDS b128 per 16 FMA4 ----
        float4 acc[4];
#pragma unroll
        for (int ti = 0; ti < 4; ++ti) acc[ti] = make_float4(0.f, 0.f, 0.f, 0.f);
#pragma unroll 4
        for (int nn = 0; nn < 256; ++nn) {
            float4 s4 = *(const float4*)&S_lds[nn * 64 + ((tg ^ (nn & 15))) * 4];
            float4 c4 = *(const float4*)&C_lds[nn * 64 + og * 4];
            FMA4(acc[0], s4.x, c4);
            FMA4(acc[1], s4.y, c4);
            FMA4(acc[2], s4.z, c4);
            FMA4(acc[3], s4.w, c4);
        }

        // ---- LayerNorm (shfl butterfly over 16 og lanes) + SiLU + store ----
#pragma unroll
        for (int ti = 0; ti < 4; ++ti) {
            float4 a = acc[ti];
            float s1 = a.x + a.y + a.z + a.w;
            float s2 = a.x * a.x + a.y * a.y + a.z * a.z + a.w * a.w;
#pragma unroll
            for (int m = 1; m < 16; m <<= 1) {
                s1 += __shfl_xor(s1, m, 64);
                s2 += __shfl_xor(s2, m, 64);
            }
            float mu = s1 * (1.f / 64.f);
            float var = s2 * (1.f / 64.f) - mu * mu;
            float rs = rsqrtf(var + 1e-5f);
            float4 yo;
            float yn;
            yn = (a.x - mu) * rs * lw4.x + lb4.x; yo.x = yn / (1.f + expf(-yn));
            yn = (a.y - mu) * rs * lw4.y + lb4.y; yo.y = yn / (1.f + expf(-yn));
            yn = (a.z - mu) * rs * lw4.z + lb4.z; yo.z = yn / (1.f + expf(-yn));
            yn = (a.w - mu) * rs * lw4.w + lb4.w; yo.w = yn / (1.f + expf(-yn));
            int t = j * CHUNK + half * 64 + tg * 4 + ti;
            *(float4*)&y_out[((size_t)b * T_LEN + t) * OCH + og * 4] = yo;
        }
    }
}

// ---------------- conv: upsample (channel-mix) + pointwise conv ----------------
// out[b][o][2tau(+1)] = sum_c w[o][2c]*y[b][tau][c] + w[o][2c+1]*y[b][T/2+tau][c] + cb[o]
__global__ __launch_bounds__(256) void k_conv(const float* __restrict__ y,
                                              const float* __restrict__ conv_w,
                                              const float* __restrict__ conv_b,
                                              float* __restrict__ out) {
    const int tb = blockIdx.x;     // tau chunk (32 taus)
    const int b  = blockIdx.y;
    const int tid = threadIdx.x;

    __shared__ float ylo[32][64];
    __shared__ float yhi[32][64];
    __shared__ float WT[128][64];  // WT[c2][o] = conv_w[o][c2]

    {   // stage W transposed
        int o = tid >> 2, kk = tid & 3;
        const float4* src = (const float4*)(conv_w + (size_t)o * 128 + kk * 32);
#pragma unroll
        for (int q = 0; q < 8; ++q) {
            float4 w4 = src[q];
            int c2 = kk * 32 + q * 4;
            WT[c2 + 0][o] = w4.x; WT[c2 + 1][o] = w4.y;
            WT[c2 + 2][o] = w4.z; WT[c2 + 3][o] = w4.w;
        }
    }
    const int tau0 = tb * 32;
    {   // stage y rows
        int r = tid >> 3, kk = tid & 7;
        const float4* sl = (const float4*)(y + (((size_t)b * T_LEN) + tau0 + r) * OCH + kk * 8);
        const float4* sh = (const float4*)(y + (((size_t)b * T_LEN) + T_LEN / 2 + tau0 + r) * OCH + kk * 8);
        float4* dl = (float4*)&ylo[r][kk * 8];
        float4* dh = (float4*)&yhi[r][kk * 8];
        dl[0] = sl[0]; dl[1] = sl[1];
        dh[0] = sh[0]; dh[1] = sh[1];
    }
    __syncthreads();

    const int o  = tid & 63;
    const int tg = tid >> 6;
    const float cb = conv_b[o];
    float* ob = out + ((size_t)b * OCH + o) * T_LEN;

    for (int i = 0; i < 8; ++i) {
        int tl = tg * 8 + i;
        float a0 = 0.f, a1 = 0.f, a2 = 0.f, a3 = 0.f;
#pragma unroll
        for (int c = 0; c < 64; c += 2) {
            a0 += WT[2*c    ][o] * ylo[tl][c];
            a1 += WT[2*c + 1][o] * yhi[tl][c];
            a2 += WT[2*c + 2][o] * ylo[tl][c + 1];
            a3 += WT[2*c + 3][o] * yhi[tl][c + 1];
        }
        float r = (a0 + a1) + (a2 + a3) + cb;
        int t2 = 2 * (tau0 + tl);
        float2 rr; rr.x = r; rr.y = r;
        *(float2*)&ob[t2] = rr;
    }
}

extern "C" void kernel_launch(void* const* d_in, const int* in_sizes, int n_in,
                              void* d_out, int out_size, void* d_ws, size_t ws_size,
                              hipStream_t stream) {
    const float* u          = (const float*)d_in[0];
    const float* raw_lambda = (const float*)d_in[1];
    const float* B_c        = (const float*)d_in[2];
    const float* C          = (const float*)d_in[3];
    const float* ln_w       = (const float*)d_in[4];
    const float* ln_b       = (const float*)d_in[5];
    const float* conv_w     = (const float*)d_in[6];
    const float* conv_b     = (const float*)d_in[7];
    float* out = (float*)d_out;
    float* ws  = (float*)d_ws;
    (void)in_sizes; (void)n_in; (void)out_size; (void)ws_size;

    // v scratch (packed bf16 pairs) lives in d_out: 8 batches * 4096 * 256 uints
    // = 33.5 MB = exactly out_size. Two phases of 8 batches; v is fully dead
    // before k_conv finally overwrites d_out with the real output.
    unsigned int* v = (unsigned int*)d_out;

    k_prep<<<1, 256, 0, stream>>>(raw_lambda, B_c, ws);
    for (int phase = 0; phase < 2; ++phase) {
        int b_off = phase * 8;
        k_pass1v<<<dim3(NCHUNK, 8), 256, 0, stream>>>(u, ws, ws + WS_ES, v, b_off);
        k_pass2 <<<8, 256, 0, stream>>>(ws, b_off);
        k_pass3v<<<dim3(NCHUNK, 8), 256, 0, stream>>>(C, ln_w, ln_b, ws, v, ws + WS_Y, b_off);
    }
    k_conv<<<dim3(T_LEN / 2 / 32, B_SZ), 256, 0, stream>>>(ws + WS_Y, conv_w, conv_b, out);
}

// Round 7
// 306.220 us; speedup vs baseline: 2.7697x; 1.1486x over previous
//
#include <hip/hip_runtime.h>
#include <math.h>

// Problem constants
#define B_SZ   16
#define CIN    64
#define T_LEN  8192
#define N_ST   256
#define OCH    64
#define CHUNK  128
#define NCHUNK (T_LEN/CHUNK)   // 64

// Workspace float offsets (total 8,667,904 floats = 34.7 MB; proven ws >= 35.7 MB)
#define WS_AD    0            // A_d            (256)
#define WS_AL    256          // A_d^128        (256)
#define WS_A32   512          // A_d^32         (256)
#define WS_BD    768          // B_d [c][n]     (64*256)
#define WS_ES    17152        // e -> sinit in-place [j][b][n] (64*16*256)
#define WS_Y     279296       // y [b][t][o]    (16*8192*64)

#define FMA4(a, s, b) { (a).x = fmaf((s),(b).x,(a).x); (a).y = fmaf((s),(b).y,(a).y); \
                        (a).z = fmaf((s),(b).z,(a).z); (a).w = fmaf((s),(b).w,(a).w); }

__device__ __forceinline__ unsigned int rne16(float x) {
    unsigned int u = __float_as_uint(x);
    return u + 0x7fffu + ((u >> 16) & 1u);      // RNE to bf16 (result in high 16 bits)
}
__device__ __forceinline__ unsigned int pack2(float even, float odd) {
    return (rne16(even) >> 16) | (rne16(odd) & 0xffff0000u);
}
__device__ __forceinline__ float bf_lo(unsigned int w) { return __uint_as_float(w << 16); }
__device__ __forceinline__ float bf_hi(unsigned int w) { return __uint_as_float(w & 0xffff0000u); }

// ---------------- prep: discretization ----------------
__global__ __launch_bounds__(256) void k_prep(const float* __restrict__ raw_lambda,
                                              const float* __restrict__ B_c,
                                              float* __restrict__ ws) {
    int n = threadIdx.x;
    float rl = raw_lambda[n];
    float sp = (rl > 20.f) ? rl : log1pf(expf(rl));   // softplus
    float lam = -sp;
    float A = expf(lam);                               // DT = 1
    float factor = (fabsf(lam) > 1e-6f) ? (A - 1.f) / lam : 1.0f;
    ws[WS_AD + n]  = A;
    ws[WS_AL + n]  = expf(lam * (float)CHUNK);
    ws[WS_A32 + n] = expf(lam * 32.f);
    float* Bd = ws + WS_BD;
    for (int c = 0; c < CIN; ++c)
        Bd[c * N_ST + n] = B_c[c * N_ST + n] * factor;
}

// ---------------- pass1: v = u.B_d (bf16-packed to v_out) + chunk carry e ----------------
// thread (tg=tid>>6, ns=tid&63): owns t = tg*32..+32, n = ns*4..+4
__global__ __launch_bounds__(256, 1) void k_pass1v(const float* __restrict__ u,
                                                   const float* __restrict__ ws,
                                                   float* __restrict__ e_out,
                                                   unsigned int* __restrict__ v_out,
                                                   int b_off) {
    const int j  = blockIdx.x;
    const int bb = blockIdx.y;          // 0..7 within phase
    const int b  = bb + b_off;          // global batch
    const int tid = threadIdx.x;
    const int tg = tid >> 6;
    const int n0 = (tid & 63) * 4;

    __shared__ float u_lds[64 * 132];    // 33.8 KB  [c][t], stride 132
    __shared__ float part[4 * 256];      //  4 KB

    {   // stage u chunk [64c][128t], coalesced 128B runs per c
        const float* ub = u + (size_t)b * CIN * T_LEN + j * CHUNK;
#pragma unroll
        for (int p = 0; p < 2; ++p) {
            int c = p * 32 + (tid >> 3), k = tid & 7;
#pragma unroll
            for (int i = 0; i < 4; ++i)
                *(float4*)&u_lds[c * 132 + k * 16 + i * 4] =
                    *(const float4*)&ub[(size_t)c * T_LEN + k * 16 + i * 4];
        }
    }
    __syncthreads();

    float4 acc[32];                      // acc[i] = v[t=tg*32+i][n0..n0+4)
#pragma unroll
    for (int i = 0; i < 32; ++i) acc[i] = make_float4(0.f, 0.f, 0.f, 0.f);

    const float* Bd = ws + WS_BD;        // read direct from L2 (contiguous 1KB/wave/c)
#pragma unroll 2
    for (int c = 0; c < 64; ++c) {
        float4 bd4 = *(const float4*)&Bd[c * N_ST + n0];
        const float* ur = &u_lds[c * 132 + tg * 32];
#pragma unroll
        for (int q = 0; q < 8; ++q) {
            float4 uq = *(const float4*)&ur[q * 4];   // wave-broadcast
            FMA4(acc[q * 4 + 0], uq.x, bd4);
            FMA4(acc[q * 4 + 1], uq.y, bd4);
            FMA4(acc[q * 4 + 2], uq.z, bd4);
            FMA4(acc[q * 4 + 3], uq.w, bd4);
        }
    }

    // ---- chunk carry: p = sum_i A^(31-i) v[i]; combine 4 t-slices with A^32 ----
    {
        float4 a4 = *(const float4*)&ws[WS_AD + n0];
        float4 p = make_float4(0.f, 0.f, 0.f, 0.f);
#pragma unroll
        for (int i = 0; i < 32; ++i) {
            p.x = fmaf(p.x, a4.x, acc[i].x);
            p.y = fmaf(p.y, a4.y, acc[i].y);
            p.z = fmaf(p.z, a4.z, acc[i].z);
            p.w = fmaf(p.w, a4.w, acc[i].w);
        }
        *(float4*)&part[tg * 256 + n0] = p;
    }
    __syncthreads();
    if (tg == 0) {
        float4 A32 = *(const float4*)&ws[WS_A32 + n0];
        float4 e  = *(const float4*)&part[0 * 256 + n0];
        float4 p1 = *(const float4*)&part[1 * 256 + n0];
        float4 p2 = *(const float4*)&part[2 * 256 + n0];
        float4 p3 = *(const float4*)&part[3 * 256 + n0];
        e.x = fmaf(e.x, A32.x, p1.x); e.y = fmaf(e.y, A32.y, p1.y);
        e.z = fmaf(e.z, A32.z, p1.z); e.w = fmaf(e.w, A32.w, p1.w);
        e.x = fmaf(e.x, A32.x, p2.x); e.y = fmaf(e.y, A32.y, p2.y);
        e.z = fmaf(e.z, A32.z, p2.z); e.w = fmaf(e.w, A32.w, p2.w);
        e.x = fmaf(e.x, A32.x, p3.x); e.y = fmaf(e.y, A32.y, p3.y);
        e.z = fmaf(e.z, A32.z, p3.z); e.w = fmaf(e.w, A32.w, p3.w);
        *(float4*)&e_out[((size_t)j * B_SZ + b) * N_ST + n0] = e;
    }

    // ---- store v as bf16 pairs: v[bb][t2][n] uint, coalesced ----
    {
        size_t base = (((size_t)bb * 4096) + (size_t)j * 64 + tg * 16) * 256 + n0;
#pragma unroll
        for (int m = 0; m < 16; ++m) {
            uint4 w;
            w.x = pack2(acc[2 * m].x, acc[2 * m + 1].x);
            w.y = pack2(acc[2 * m].y, acc[2 * m + 1].y);
            w.z = pack2(acc[2 * m].z, acc[2 * m + 1].z);
            w.w = pack2(acc[2 * m].w, acc[2 * m + 1].w);
            *(uint4*)&v_out[base + (size_t)m * 256] = w;
        }
    }
}

// ---------------- pass2: chunk-prefix combine, e -> sinit in place ----------------
__global__ __launch_bounds__(256) void k_pass2(float* __restrict__ ws, int b_off) {
    const int b = blockIdx.x + b_off;
    const int n = threadIdx.x;
    const float AL = ws[WS_AL + n];
    float* es = ws + WS_ES;
    float ev[NCHUNK];
#pragma unroll
    for (int j = 0; j < NCHUNK; ++j)     // all loads issued up-front (independent)
        ev[j] = es[((size_t)j * B_SZ + b) * N_ST + n];
    float s = 0.f;
#pragma unroll
    for (int j = 0; j < NCHUNK; ++j) {
        es[((size_t)j * B_SZ + b) * N_ST + n] = s;   // sinit: state BEFORE chunk j
        s = s * AL + ev[j];
    }
}

// ---------------- pass3: scan (v from global) + S.C + LN + SiLU ----------------
// scan: thread = n. projection: thread (og=tid&15 -> 4 o's, tg=tid>>4 -> 4 t's)
// S_lds dense [256][64] with 16B-unit XOR swizzle: col4' = col4 ^ (row & 15)
__global__ __launch_bounds__(256, 1) void k_pass3v(const float* __restrict__ C,
                                                   const float* __restrict__ ln_w,
                                                   const float* __restrict__ ln_b,
                                                   const float* __restrict__ ws,
                                                   const unsigned int* __restrict__ v_in,
                                                   float* __restrict__ y_out,
                                                   int b_off) {
    const int j  = blockIdx.x;
    const int bb = blockIdx.y;
    const int b  = bb + b_off;
    const int tid = threadIdx.x;

    __shared__ float S_lds[256 * 64];    // 64 KB [n][t] swizzled
    __shared__ float C_lds[256 * 64];    // 64 KB [n][o] flat   => 128 KB total

    {   // stage C, coalesced flat copy
#pragma unroll
        for (int g = 0; g < 16; ++g)
            ((float4*)C_lds)[g * 256 + tid] = ((const float4*)C)[g * 256 + tid];
    }

    const int n = tid;
    const float A = ws[WS_AD + n];
    float s = ws[WS_ES + ((size_t)j * B_SZ + b) * N_ST + n];

    const int og = tid & 15;             // o = og*4..+4
    const int tg = tid >> 4;             // t_loc = tg*4..+4 within 64-t half
    float4 lw4 = *(const float4*)&ln_w[og * 4];
    float4 lb4 = *(const float4*)&ln_b[og * 4];

    for (int half = 0; half < 2; ++half) {
        if (half) __syncthreads();       // prev projection done before S overwrite

        // ---- scan 64 t, v from global (L2/L3-resident), deposit S[n][t] swizzled ----
        {
            size_t vb = (((size_t)bb * 4096) + (size_t)j * 64 + half * 32) * 256 + n;
            unsigned int vv[32];
#pragma unroll
            for (int i = 0; i < 32; ++i) vv[i] = v_in[vb + (size_t)i * 256];
#pragma unroll
            for (int q = 0; q < 16; ++q) {
                unsigned int w0 = vv[2 * q], w1 = vv[2 * q + 1];
                float4 s4;
                s = fmaf(s, A, bf_lo(w0)); s4.x = s;
                s = fmaf(s, A, bf_hi(w0)); s4.y = s;
                s = fmaf(s, A, bf_lo(w1)); s4.z = s;
                s = fmaf(s, A, bf_hi(w1)); s4.w = s;
                *(float4*)&S_lds[n * 64 + (q ^ (n & 15)) * 4] = s4;
            }
        }
        __syncthreads();

        // ---- projection: acc[ti][4o], 2 LDS b128 per 16 FMA4 ----
        float4 acc[4];
#pragma unroll
        for (int ti = 0; ti < 4; ++ti) acc[ti] = make_float4(0.f, 0.f, 0.f, 0.f);
#pragma unroll 4
        for (int nn = 0; nn < 256; ++nn) {
            float4 s4 = *(const float4*)&S_lds[nn * 64 + ((tg ^ (nn & 15))) * 4];
            float4 c4 = *(const float4*)&C_lds[nn * 64 + og * 4];
            FMA4(acc[0], s4.x, c4);
            FMA4(acc[1], s4.y, c4);
            FMA4(acc[2], s4.z, c4);
            FMA4(acc[3], s4.w, c4);
        }

        // ---- LayerNorm (shfl butterfly over 16 og lanes) + SiLU + store ----
#pragma unroll
        for (int ti = 0; ti < 4; ++ti) {
            float4 a = acc[ti];
            float s1 = a.x + a.y + a.z + a.w;
            float s2 = a.x * a.x + a.y * a.y + a.z * a.z + a.w * a.w;
#pragma unroll
            for (int m = 1; m < 16; m <<= 1) {
                s1 += __shfl_xor(s1, m, 64);
                s2 += __shfl_xor(s2, m, 64);
            }
            float mu = s1 * (1.f / 64.f);
            float var = s2 * (1.f / 64.f) - mu * mu;
            float rs = rsqrtf(var + 1e-5f);
            float4 yo;
            float yn;
            yn = (a.x - mu) * rs * lw4.x + lb4.x; yo.x = yn / (1.f + expf(-yn));
            yn = (a.y - mu) * rs * lw4.y + lb4.y; yo.y = yn / (1.f + expf(-yn));
            yn = (a.z - mu) * rs * lw4.z + lb4.z; yo.z = yn / (1.f + expf(-yn));
            yn = (a.w - mu) * rs * lw4.w + lb4.w; yo.w = yn / (1.f + expf(-yn));
            int t = j * CHUNK + half * 64 + tg * 4 + ti;
            *(float4*)&y_out[((size_t)b * T_LEN + t) * OCH + og * 4] = yo;
        }
    }
}

// ---------------- conv2: upsample (channel-mix) + pointwise conv, register-tiled GEMM ----
// out[b][o][2tau(+1)] = sum_c2 W[o][c2] * V[c2][tau] + cb[o]
//   V[2c][tau] = y[b][tau][c], V[2c+1][tau] = y[b][T/2+tau][c]
// Block: 128 taus. Thread (og=tid&7 -> 8 o's, tg=tid>>3 -> 4 taus): 3 b128 per 32 FMA.
__global__ __launch_bounds__(256, 1) void k_conv2(const float* __restrict__ y,
                                                  const float* __restrict__ conv_w,
                                                  const float* __restrict__ conv_b,
                                                  float* __restrict__ out) {
    const int tb = blockIdx.x;     // 32 tau-blocks
    const int b  = blockIdx.y;
    const int tid = threadIdx.x;

    __shared__ float V[128 * 128];   // 64 KB  V[c2][tau]
    __shared__ float WT[128 * 64];   // 32 KB  WT[c2][o]

    {   // stage WT transposed: conv_w[o][c2] -> WT[c2][o]
        int o = tid >> 2, kk = tid & 3;
        const float4* src = (const float4*)(conv_w + (size_t)o * 128 + kk * 32);
#pragma unroll
        for (int q = 0; q < 8; ++q) {
            float4 w4 = src[q];
            int c2 = kk * 32 + q * 4;
            WT[(c2 + 0) * 64 + o] = w4.x;
            WT[(c2 + 1) * 64 + o] = w4.y;
            WT[(c2 + 2) * 64 + o] = w4.z;
            WT[(c2 + 3) * 64 + o] = w4.w;
        }
    }
    const int tau0 = tb * 128;
    {   // stage V: lanes along tau -> conflict-free b32 writes; 4 waves cover full 64B rows
        int lt = tid & 63;           // tau within 64-group
        int cg = tid >> 6;           // wave id -> c4 offset
        const float* ybl = y + ((size_t)b * T_LEN + tau0) * OCH;
        const float* ybh = y + ((size_t)b * T_LEN + T_LEN / 2 + tau0) * OCH;
#pragma unroll
        for (int it = 0; it < 8; ++it) {
            int tau = (it & 1) * 64 + lt;
            int c4  = (it >> 1) * 4 + cg;          // 0..15
            float4 lo = *(const float4*)&ybl[(size_t)tau * OCH + c4 * 4];
            float4 hi = *(const float4*)&ybh[(size_t)tau * OCH + c4 * 4];
            int c2 = c4 * 8;
            V[(c2 + 0) * 128 + tau] = lo.x;
            V[(c2 + 1) * 128 + tau] = hi.x;
            V[(c2 + 2) * 128 + tau] = lo.y;
            V[(c2 + 3) * 128 + tau] = hi.y;
            V[(c2 + 4) * 128 + tau] = lo.z;
            V[(c2 + 5) * 128 + tau] = hi.z;
            V[(c2 + 6) * 128 + tau] = lo.w;
            V[(c2 + 7) * 128 + tau] = hi.w;
        }
    }
    __syncthreads();

    const int og = tid & 7;          // o = og*8..+8
    const int tg = tid >> 3;         // tau = tg*4..+4
    float4 a0[4], a1[4];
#pragma unroll
    for (int ti = 0; ti < 4; ++ti) {
        a0[ti] = make_float4(0.f, 0.f, 0.f, 0.f);
        a1[ti] = make_float4(0.f, 0.f, 0.f, 0.f);
    }

#pragma unroll 4
    for (int c2 = 0; c2 < 128; ++c2) {
        float4 v4 = *(const float4*)&V[c2 * 128 + tg * 4];        // 8-addr broadcast
        float4 w0 = *(const float4*)&WT[c2 * 64 + og * 8];        // consecutive 16B
        float4 w1 = *(const float4*)&WT[c2 * 64 + og * 8 + 4];
        FMA4(a0[0], v4.x, w0); FMA4(a1[0], v4.x, w1);
        FMA4(a0[1], v4.y, w0); FMA4(a1[1], v4.y, w1);
        FMA4(a0[2], v4.z, w0); FMA4(a1[2], v4.z, w1);
        FMA4(a0[3], v4.w, w0); FMA4(a1[3], v4.w, w1);
    }

    // epilogue: + bias, duplicate to (2tau, 2tau+1)
    float4 cb0 = *(const float4*)&conv_b[og * 8];
    float4 cb1 = *(const float4*)&conv_b[og * 8 + 4];
    float* ob = out + (size_t)b * OCH * T_LEN + (size_t)og * 8 * T_LEN;
#pragma unroll
    for (int ti = 0; ti < 4; ++ti) {
        int t2 = 2 * (tau0 + tg * 4 + ti);
        float r;
        float2 rr;
        r = a0[ti].x + cb0.x; rr.x = r; rr.y = r; *(float2*)&ob[0 * T_LEN + t2] = rr;
        r = a0[ti].y + cb0.y; rr.x = r; rr.y = r; *(float2*)&ob[1 * T_LEN + t2] = rr;
        r = a0[ti].z + cb0.z; rr.x = r; rr.y = r; *(float2*)&ob[2 * T_LEN + t2] = rr;
        r = a0[ti].w + cb0.w; rr.x = r; rr.y = r; *(float2*)&ob[3 * T_LEN + t2] = rr;
        r = a1[ti].x + cb1.x; rr.x = r; rr.y = r; *(float2*)&ob[4 * T_LEN + t2] = rr;
        r = a1[ti].y + cb1.y; rr.x = r; rr.y = r; *(float2*)&ob[5 * T_LEN + t2] = rr;
        r = a1[ti].z + cb1.z; rr.x = r; rr.y = r; *(float2*)&ob[6 * T_LEN + t2] = rr;
        r = a1[ti].w + cb1.w; rr.x = r; rr.y = r; *(float2*)&ob[7 * T_LEN + t2] = rr;
    }
}

extern "C" void kernel_launch(void* const* d_in, const int* in_sizes, int n_in,
                              void* d_out, int out_size, void* d_ws, size_t ws_size,
                              hipStream_t stream) {
    const float* u          = (const float*)d_in[0];
    const float* raw_lambda = (const float*)d_in[1];
    const float* B_c        = (const float*)d_in[2];
    const float* C          = (const float*)d_in[3];
    const float* ln_w       = (const float*)d_in[4];
    const float* ln_b       = (const float*)d_in[5];
    const float* conv_w     = (const float*)d_in[6];
    const float* conv_b     = (const float*)d_in[7];
    float* out = (float*)d_out;
    float* ws  = (float*)d_ws;
    (void)in_sizes; (void)n_in; (void)out_size; (void)ws_size;

    // v scratch (packed bf16 pairs) lives in d_out: 8 batches * 4096 * 256 uints
    // = 33.5 MB = exactly out_size. Two phases of 8 batches; v is fully dead
    // before k_conv2 finally overwrites d_out with the real output.
    unsigned int* v = (unsigned int*)d_out;

    k_prep<<<1, 256, 0, stream>>>(raw_lambda, B_c, ws);
    for (int phase = 0; phase < 2; ++phase) {
        int b_off = phase * 8;
        k_pass1v<<<dim3(NCHUNK, 8), 256, 0, stream>>>(u, ws, ws + WS_ES, v, b_off);
        k_pass2 <<<8, 256, 0, stream>>>(ws, b_off);
        k_pass3v<<<dim3(NCHUNK, 8), 256, 0, stream>>>(C, ln_w, ln_b, ws, v, ws + WS_Y, b_off);
    }
    k_conv2<<<dim3(T_LEN / 2 / 128, B_SZ), 256, 0, stream>>>(ws + WS_Y, conv_w, conv_b, out);
}

// Round 9
// 289.432 us; speedup vs baseline: 2.9303x; 1.0580x over previous
//
#include <hip/hip_runtime.h>
#include <math.h>

// Problem constants
#define B_SZ   16
#define CIN    64
#define T_LEN  8192
#define N_ST   256
#define OCH    64
#define CHUNK  128
#define NCHUNK (T_LEN/CHUNK)   // 64

// Workspace float offsets (total 8,667,904 floats = 34.7 MB; proven ws >= 35.7 MB)
#define WS_AD    0            // A_d            (256)
#define WS_AL    256          // A_d^128        (256)
#define WS_A32   512          // A_d^32         (256)
#define WS_BD    768          // B_d [c][n]     (64*256)
#define WS_ES    17152        // e -> sinit in-place [j][b][n] (64*16*256)
#define WS_Y     279296       // y [b][t][o]    (16*8192*64)

#define FMA4(a, s, b) { (a).x = fmaf((s),(b).x,(a).x); (a).y = fmaf((s),(b).y,(a).y); \
                        (a).z = fmaf((s),(b).z,(a).z); (a).w = fmaf((s),(b).w,(a).w); }

__device__ __forceinline__ unsigned int rne16(float x) {
    unsigned int u = __float_as_uint(x);
    return u + 0x7fffu + ((u >> 16) & 1u);      // RNE to bf16 (result in high 16 bits)
}
__device__ __forceinline__ unsigned int pack2(float even, float odd) {
    return (rne16(even) >> 16) | (rne16(odd) & 0xffff0000u);
}
__device__ __forceinline__ float bf_lo(unsigned int w) { return __uint_as_float(w << 16); }
__device__ __forceinline__ float bf_hi(unsigned int w) { return __uint_as_float(w & 0xffff0000u); }

// ---------------- prep: discretization ----------------
__global__ __launch_bounds__(256) void k_prep(const float* __restrict__ raw_lambda,
                                              const float* __restrict__ B_c,
                                              float* __restrict__ ws) {
    int n = threadIdx.x;
    float rl = raw_lambda[n];
    float sp = (rl > 20.f) ? rl : log1pf(expf(rl));   // softplus
    float lam = -sp;
    float A = expf(lam);                               // DT = 1
    float factor = (fabsf(lam) > 1e-6f) ? (A - 1.f) / lam : 1.0f;
    ws[WS_AD + n]  = A;
    ws[WS_AL + n]  = expf(lam * (float)CHUNK);
    ws[WS_A32 + n] = expf(lam * 32.f);
    float* Bd = ws + WS_BD;
    for (int c = 0; c < CIN; ++c)
        Bd[c * N_ST + n] = B_c[c * N_ST + n] * factor;
}

// ---------------- pass1: v = u.B_d (bf16-packed to v_out) + chunk carry e ----------------
// thread (tg=tid>>6, ns=tid&63): owns t = tg*32..+32, n = ns*4..+4
__global__ __launch_bounds__(256, 1) void k_pass1v(const float* __restrict__ u,
                                                   const float* __restrict__ ws,
                                                   float* __restrict__ e_out,
                                                   unsigned int* __restrict__ v_out,
                                                   int b_off) {
    const int j  = blockIdx.x;
    const int bb = blockIdx.y;          // 0..7 within phase
    const int b  = bb + b_off;          // global batch
    const int tid = threadIdx.x;
    const int tg = tid >> 6;
    const int n0 = (tid & 63) * 4;

    __shared__ float u_lds[64 * 132];    // 33.8 KB  [c][t], stride 132
    __shared__ float part[4 * 256];      //  4 KB

    {   // stage u chunk [64c][128t], coalesced 128B runs per c
        const float* ub = u + (size_t)b * CIN * T_LEN + j * CHUNK;
#pragma unroll
        for (int p = 0; p < 2; ++p) {
            int c = p * 32 + (tid >> 3), k = tid & 7;
#pragma unroll
            for (int i = 0; i < 4; ++i)
                *(float4*)&u_lds[c * 132 + k * 16 + i * 4] =
                    *(const float4*)&ub[(size_t)c * T_LEN + k * 16 + i * 4];
        }
    }
    __syncthreads();

    float4 acc[32];                      // acc[i] = v[t=tg*32+i][n0..n0+4)
#pragma unroll
    for (int i = 0; i < 32; ++i) acc[i] = make_float4(0.f, 0.f, 0.f, 0.f);

    const float* Bd = ws + WS_BD;        // read direct from L2 (contiguous 1KB/wave/c)
#pragma unroll 2
    for (int c = 0; c < 64; ++c) {
        float4 bd4 = *(const float4*)&Bd[c * N_ST + n0];
        const float* ur = &u_lds[c * 132 + tg * 32];
#pragma unroll
        for (int q = 0; q < 8; ++q) {
            float4 uq = *(const float4*)&ur[q * 4];   // wave-broadcast
            FMA4(acc[q * 4 + 0], uq.x, bd4);
            FMA4(acc[q * 4 + 1], uq.y, bd4);
            FMA4(acc[q * 4 + 2], uq.z, bd4);
            FMA4(acc[q * 4 + 3], uq.w, bd4);
        }
    }

    // ---- chunk carry: p = sum_i A^(31-i) v[i]; combine 4 t-slices with A^32 ----
    {
        float4 a4 = *(const float4*)&ws[WS_AD + n0];
        float4 p = make_float4(0.f, 0.f, 0.f, 0.f);
#pragma unroll
        for (int i = 0; i < 32; ++i) {
            p.x = fmaf(p.x, a4.x, acc[i].x);
            p.y = fmaf(p.y, a4.y, acc[i].y);
            p.z = fmaf(p.z, a4.z, acc[i].z);
            p.w = fmaf(p.w, a4.w, acc[i].w);
        }
        *(float4*)&part[tg * 256 + n0] = p;
    }
    __syncthreads();
    if (tg == 0) {
        float4 A32 = *(const float4*)&ws[WS_A32 + n0];
        float4 e  = *(const float4*)&part[0 * 256 + n0];
        float4 p1 = *(const float4*)&part[1 * 256 + n0];
        float4 p2 = *(const float4*)&part[2 * 256 + n0];
        float4 p3 = *(const float4*)&part[3 * 256 + n0];
        e.x = fmaf(e.x, A32.x, p1.x); e.y = fmaf(e.y, A32.y, p1.y);
        e.z = fmaf(e.z, A32.z, p1.z); e.w = fmaf(e.w, A32.w, p1.w);
        e.x = fmaf(e.x, A32.x, p2.x); e.y = fmaf(e.y, A32.y, p2.y);
        e.z = fmaf(e.z, A32.z, p2.z); e.w = fmaf(e.w, A32.w, p2.w);
        e.x = fmaf(e.x, A32.x, p3.x); e.y = fmaf(e.y, A32.y, p3.y);
        e.z = fmaf(e.z, A32.z, p3.z); e.w = fmaf(e.w, A32.w, p3.w);
        *(float4*)&e_out[((size_t)j * B_SZ + b) * N_ST + n0] = e;
    }

    // ---- store v as bf16 pairs: v[bb][t2][n] uint, coalesced ----
    {
        size_t base = (((size_t)bb * 4096) + (size_t)j * 64 + tg * 16) * 256 + n0;
#pragma unroll
        for (int m = 0; m < 16; ++m) {
            uint4 w;
            w.x = pack2(acc[2 * m].x, acc[2 * m + 1].x);
            w.y = pack2(acc[2 * m].y, acc[2 * m + 1].y);
            w.z = pack2(acc[2 * m].z, acc[2 * m + 1].z);
            w.w = pack2(acc[2 * m].w, acc[2 * m + 1].w);
            *(uint4*)&v_out[base + (size_t)m * 256] = w;
        }
    }
}

// ---------------- pass2: chunk-prefix combine, e -> sinit in place ----------------
__global__ __launch_bounds__(256) void k_pass2(float* __restrict__ ws, int b_off) {
    const int b = blockIdx.x + b_off;
    const int n = threadIdx.x;
    const float AL = ws[WS_AL + n];
    float* es = ws + WS_ES;
    float ev[NCHUNK];
#pragma unroll
    for (int j = 0; j < NCHUNK; ++j)     // all loads issued up-front (independent)
        ev[j] = es[((size_t)j * B_SZ + b) * N_ST + n];
    float s = 0.f;
#pragma unroll
    for (int j = 0; j < NCHUNK; ++j) {
        es[((size_t)j * B_SZ + b) * N_ST + n] = s;   // sinit: state BEFORE chunk j
        s = s * AL + ev[j];
    }
}

// ---------------- pass3w: scan + bf16-S unified projection + LN + SiLU ----------------
// Scan: thread = n, full 128-t chain, S packed bf16 pairs -> S_lds [256n][128t].
// Projection: thread (og=tid&15 -> o=og*4..+4, tg=tid>>4 -> t=tg*8..+8), ONE pass
// over nn (C read once per nn). uint4-level XOR swizzle: store cu^=(n&15), read tg^=(nn&15).
__global__ __launch_bounds__(256, 1) void k_pass3w(const float* __restrict__ C,
                                                   const float* __restrict__ ln_w,
                                                   const float* __restrict__ ln_b,
                                                   const float* __restrict__ ws,
                                                   const unsigned int* __restrict__ v_in,
                                                   float* __restrict__ y_out,
                                                   int b_off) {
    const int j  = blockIdx.x;
    const int bb = blockIdx.y;
    const int b  = bb + b_off;
    const int tid = threadIdx.x;

    __shared__ unsigned int S_u4[256 * 16 * 4]; // 64 KB: [n][16 uint4] = 128 bf16 t-values
    __shared__ float C_lds[256 * 64];           // 64 KB  [n][o] flat   => 128 KB total

    {   // stage C, coalesced flat copy
#pragma unroll
        for (int g = 0; g < 16; ++g)
            ((float4*)C_lds)[g * 256 + tid] = ((const float4*)C)[g * 256 + tid];
    }

    // ---- scan: full 128-t chain for n = tid, deposit packed bf16 pairs ----
    {
        const int n = tid;
        const float A = ws[WS_AD + n];
        float s = ws[WS_ES + ((size_t)j * B_SZ + b) * N_ST + n];
        size_t vb = (((size_t)bb * 4096) + (size_t)j * 64) * 256 + n;
        unsigned int vv[64];
#pragma unroll
        for (int i = 0; i < 64; ++i) vv[i] = v_in[vb + (size_t)i * 256];
        unsigned int* srow = &S_u4[n * 64];
#pragma unroll
        for (int cu = 0; cu < 16; ++cu) {
            uint4 w4;
            float e0, o0;
            unsigned int w;
            w = vv[cu * 4 + 0];
            s = fmaf(s, A, bf_lo(w)); e0 = s;
            s = fmaf(s, A, bf_hi(w)); o0 = s;  w4.x = pack2(e0, o0);
            w = vv[cu * 4 + 1];
            s = fmaf(s, A, bf_lo(w)); e0 = s;
            s = fmaf(s, A, bf_hi(w)); o0 = s;  w4.y = pack2(e0, o0);
            w = vv[cu * 4 + 2];
            s = fmaf(s, A, bf_lo(w)); e0 = s;
            s = fmaf(s, A, bf_hi(w)); o0 = s;  w4.z = pack2(e0, o0);
            w = vv[cu * 4 + 3];
            s = fmaf(s, A, bf_lo(w)); e0 = s;
            s = fmaf(s, A, bf_hi(w)); o0 = s;  w4.w = pack2(e0, o0);
            *(uint4*)&srow[(cu ^ (n & 15)) * 4] = w4;   // swizzled uint4 slot
        }
    }
    __syncthreads();

    // ---- projection: acc[8t][4o]; per nn: 1 S-b128 (8 t) + 1 C-b128 (4 o) -> 32 fma ----
    const int og = tid & 15;             // o = og*4..+4
    const int tg = tid >> 4;             // t = tg*8..+8
    float4 acc[8];
#pragma unroll
    for (int k = 0; k < 8; ++k) acc[k] = make_float4(0.f, 0.f, 0.f, 0.f);

#pragma unroll 4
    for (int nn = 0; nn < 256; ++nn) {
        uint4 sp = *(const uint4*)&S_u4[nn * 64 + ((tg ^ (nn & 15))) * 4];
        float4 c4 = *(const float4*)&C_lds[nn * 64 + og * 4];
        FMA4(acc[0], bf_lo(sp.x), c4);
        FMA4(acc[1], bf_hi(sp.x), c4);
        FMA4(acc[2], bf_lo(sp.y), c4);
        FMA4(acc[3], bf_hi(sp.y), c4);
        FMA4(acc[4], bf_lo(sp.z), c4);
        FMA4(acc[5], bf_hi(sp.z), c4);
        FMA4(acc[6], bf_lo(sp.w), c4);
        FMA4(acc[7], bf_hi(sp.w), c4);
    }

    // ---- LayerNorm (shfl butterfly over 16 og lanes) + SiLU + store ----
    float4 lw4 = *(const float4*)&ln_w[og * 4];
    float4 lb4 = *(const float4*)&ln_b[og * 4];
#pragma unroll
    for (int ti = 0; ti < 8; ++ti) {
        float4 a = acc[ti];
        float s1 = a.x + a.y + a.z + a.w;
        float s2 = a.x * a.x + a.y * a.y + a.z * a.z + a.w * a.w;
#pragma unroll
        for (int m = 1; m < 16; m <<= 1) {
            s1 += __shfl_xor(s1, m, 64);
            s2 += __shfl_xor(s2, m, 64);
        }
        float mu = s1 * (1.f / 64.f);
        float var = s2 * (1.f / 64.f) - mu * mu;
        float rs = rsqrtf(var + 1e-5f);
        float4 yo;
        float yn;
        yn = (a.x - mu) * rs * lw4.x + lb4.x; yo.x = yn / (1.f + expf(-yn));
        yn = (a.y - mu) * rs * lw4.y + lb4.y; yo.y = yn / (1.f + expf(-yn));
        yn = (a.z - mu) * rs * lw4.z + lb4.z; yo.z = yn / (1.f + expf(-yn));
        yn = (a.w - mu) * rs * lw4.w + lb4.w; yo.w = yn / (1.f + expf(-yn));
        int t = j * CHUNK + tg * 8 + ti;
        *(float4*)&y_out[((size_t)b * T_LEN + t) * OCH + og * 4] = yo;
    }
}

// ---------------- conv2: upsample (channel-mix) + pointwise conv, register-tiled GEMM ----
// out[b][o][2tau(+1)] = sum_c2 W[o][c2] * V[c2][tau] + cb[o]
//   V[2c][tau] = y[b][tau][c], V[2c+1][tau] = y[b][T/2+tau][c]
// Block: 128 taus. Thread (og=tid&7 -> 8 o's, tg=tid>>3 -> 4 taus): 3 b128 per 32 FMA.
__global__ __launch_bounds__(256, 1) void k_conv2(const float* __restrict__ y,
                                                  const float* __restrict__ conv_w,
                                                  const float* __restrict__ conv_b,
                                                  float* __restrict__ out) {
    const int tb = blockIdx.x;     // 32 tau-blocks
    const int b  = blockIdx.y;
    const int tid = threadIdx.x;

    __shared__ float V[128 * 128];   // 64 KB  V[c2][tau]
    __shared__ float WT[128 * 64];   // 32 KB  WT[c2][o]

    {   // stage WT transposed: conv_w[o][c2] -> WT[c2][o]
        int o = tid >> 2, kk = tid & 3;
        const float4* src = (const float4*)(conv_w + (size_t)o * 128 + kk * 32);
#pragma unroll
        for (int q = 0; q < 8; ++q) {
            float4 w4 = src[q];
            int c2 = kk * 32 + q * 4;
            WT[(c2 + 0) * 64 + o] = w4.x;
            WT[(c2 + 1) * 64 + o] = w4.y;
            WT[(c2 + 2) * 64 + o] = w4.z;
            WT[(c2 + 3) * 64 + o] = w4.w;
        }
    }
    const int tau0 = tb * 128;
    {   // stage V: lanes along tau -> conflict-free b32 writes; 4 waves cover full 64B rows
        int lt = tid & 63;           // tau within 64-group
        int cg = tid >> 6;           // wave id -> c4 offset
        const float* ybl = y + ((size_t)b * T_LEN + tau0) * OCH;
        const float* ybh = y + ((size_t)b * T_LEN + T_LEN / 2 + tau0) * OCH;
#pragma unroll
        for (int it = 0; it < 8; ++it) {
            int tau = (it & 1) * 64 + lt;
            int c4  = (it >> 1) * 4 + cg;          // 0..15
            float4 lo = *(const float4*)&ybl[(size_t)tau * OCH + c4 * 4];
            float4 hi = *(const float4*)&ybh[(size_t)tau * OCH + c4 * 4];
            int c2 = c4 * 8;
            V[(c2 + 0) * 128 + tau] = lo.x;
            V[(c2 + 1) * 128 + tau] = hi.x;
            V[(c2 + 2) * 128 + tau] = lo.y;
            V[(c2 + 3) * 128 + tau] = hi.y;
            V[(c2 + 4) * 128 + tau] = lo.z;
            V[(c2 + 5) * 128 + tau] = hi.z;
            V[(c2 + 6) * 128 + tau] = lo.w;
            V[(c2 + 7) * 128 + tau] = hi.w;
        }
    }
    __syncthreads();

    const int og = tid & 7;          // o = og*8..+8
    const int tg = tid >> 3;         // tau = tg*4..+4
    float4 a0[4], a1[4];
#pragma unroll
    for (int ti = 0; ti < 4; ++ti) {
        a0[ti] = make_float4(0.f, 0.f, 0.f, 0.f);
        a1[ti] = make_float4(0.f, 0.f, 0.f, 0.f);
    }

#pragma unroll 4
    for (int c2 = 0; c2 < 128; ++c2) {
        float4 v4 = *(const float4*)&V[c2 * 128 + tg * 4];        // 8-addr broadcast
        float4 w0 = *(const float4*)&WT[c2 * 64 + og * 8];        // consecutive 16B
        float4 w1 = *(const float4*)&WT[c2 * 64 + og * 8 + 4];
        FMA4(a0[0], v4.x, w0); FMA4(a1[0], v4.x, w1);
        FMA4(a0[1], v4.y, w0); FMA4(a1[1], v4.y, w1);
        FMA4(a0[2], v4.z, w0); FMA4(a1[2], v4.z, w1);
        FMA4(a0[3], v4.w, w0); FMA4(a1[3], v4.w, w1);
    }

    // epilogue: + bias, duplicate to (2tau, 2tau+1)
    float4 cb0 = *(const float4*)&conv_b[og * 8];
    float4 cb1 = *(const float4*)&conv_b[og * 8 + 4];
    float* ob = out + (size_t)b * OCH * T_LEN + (size_t)og * 8 * T_LEN;
#pragma unroll
    for (int ti = 0; ti < 4; ++ti) {
        int t2 = 2 * (tau0 + tg * 4 + ti);
        float r;
        float2 rr;
        r = a0[ti].x + cb0.x; rr.x = r; rr.y = r; *(float2*)&ob[0 * T_LEN + t2] = rr;
        r = a0[ti].y + cb0.y; rr.x = r; rr.y = r; *(float2*)&ob[1 * T_LEN + t2] = rr;
        r = a0[ti].z + cb0.z; rr.x = r; rr.y = r; *(float2*)&ob[2 * T_LEN + t2] = rr;
        r = a0[ti].w + cb0.w; rr.x = r; rr.y = r; *(float2*)&ob[3 * T_LEN + t2] = rr;
        r = a1[ti].x + cb1.x; rr.x = r; rr.y = r; *(float2*)&ob[4 * T_LEN + t2] = rr;
        r = a1[ti].y + cb1.y; rr.x = r; rr.y = r; *(float2*)&ob[5 * T_LEN + t2] = rr;
        r = a1[ti].z + cb1.z; rr.x = r; rr.y = r; *(float2*)&ob[6 * T_LEN + t2] = rr;
        r = a1[ti].w + cb1.w; rr.x = r; rr.y = r; *(float2*)&ob[7 * T_LEN + t2] = rr;
    }
}

extern "C" void kernel_launch(void* const* d_in, const int* in_sizes, int n_in,
                              void* d_out, int out_size, void* d_ws, size_t ws_size,
                              hipStream_t stream) {
    const float* u          = (const float*)d_in[0];
    const float* raw_lambda = (const float*)d_in[1];
    const float* B_c        = (const float*)d_in[2];
    const float* C          = (const float*)d_in[3];
    const float* ln_w       = (const float*)d_in[4];
    const float* ln_b       = (const float*)d_in[5];
    const float* conv_w     = (const float*)d_in[6];
    const float* conv_b     = (const float*)d_in[7];
    float* out = (float*)d_out;
    float* ws  = (float*)d_ws;
    (void)in_sizes; (void)n_in; (void)out_size; (void)ws_size;

    // v scratch (packed bf16 pairs) lives in d_out: 8 batches * 4096 * 256 uints
    // = 33.5 MB = exactly out_size. Two phases of 8 batches; v is fully dead
    // before k_conv2 finally overwrites d_out with the real output.
    unsigned int* v = (unsigned int*)d_out;

    k_prep<<<1, 256, 0, stream>>>(raw_lambda, B_c, ws);
    for (int phase = 0; phase < 2; ++phase) {
        int b_off = phase * 8;
        k_pass1v<<<dim3(NCHUNK, 8), 256, 0, stream>>>(u, ws, ws + WS_ES, v, b_off);
        k_pass2 <<<8, 256, 0, stream>>>(ws, b_off);
        k_pass3w<<<dim3(NCHUNK, 8), 256, 0, stream>>>(C, ln_w, ln_b, ws, v, ws + WS_Y, b_off);
    }
    k_conv2<<<dim3(T_LEN / 2 / 128, B_SZ), 256, 0, stream>>>(ws + WS_Y, conv_w, conv_b, out);
}

// Round 11
// 233.673 us; speedup vs baseline: 3.6296x; 1.2386x over previous
//
#include <hip/hip_runtime.h>
#include <math.h>

// Problem constants
#define B_SZ   16
#define CIN    64
#define T_LEN  8192
#define N_ST   256
#define OCH    64
#define CHUNK  128
#define NCHUNK (T_LEN/CHUNK)   // 64

// Workspace float offsets (total 8,667,904 floats = 34.7 MB; proven ws >= 35.7 MB)
#define WS_AD    0            // A_d            (256)
#define WS_AL    256          // A_d^128        (256)
#define WS_A32   512          // A_d^32         (256)
#define WS_BD    768          // B_d [c][n]     (64*256)
#define WS_ES    17152        // e -> sinit in-place [j][b][n] (64*16*256)
#define WS_Y     279296       // y [b][t][o]    (16*8192*64)

#define FMA4(a, s, b) { (a).x = fmaf((s),(b).x,(a).x); (a).y = fmaf((s),(b).y,(a).y); \
                        (a).z = fmaf((s),(b).z,(a).z); (a).w = fmaf((s),(b).w,(a).w); }

typedef __attribute__((ext_vector_type(8))) short s8v;
typedef __attribute__((ext_vector_type(4))) float f4v;

__device__ __forceinline__ unsigned int rne16(float x) {
    unsigned int u = __float_as_uint(x);
    return u + 0x7fffu + ((u >> 16) & 1u);      // RNE to bf16 (result in high 16 bits)
}
__device__ __forceinline__ unsigned int pack2(float even, float odd) {
    return (rne16(even) >> 16) | (rne16(odd) & 0xffff0000u);
}
__device__ __forceinline__ float bf_lo(unsigned int w) { return __uint_as_float(w << 16); }
__device__ __forceinline__ float bf_hi(unsigned int w) { return __uint_as_float(w & 0xffff0000u); }

// ---------------- prep: discretization ----------------
__global__ __launch_bounds__(256) void k_prep(const float* __restrict__ raw_lambda,
                                              const float* __restrict__ B_c,
                                              float* __restrict__ ws) {
    int n = threadIdx.x;
    float rl = raw_lambda[n];
    float sp = (rl > 20.f) ? rl : log1pf(expf(rl));   // softplus
    float lam = -sp;
    float A = expf(lam);                               // DT = 1
    float factor = (fabsf(lam) > 1e-6f) ? (A - 1.f) / lam : 1.0f;
    ws[WS_AD + n]  = A;
    ws[WS_AL + n]  = expf(lam * (float)CHUNK);
    ws[WS_A32 + n] = expf(lam * 32.f);
    float* Bd = ws + WS_BD;
    for (int c = 0; c < CIN; ++c)
        Bd[c * N_ST + n] = B_c[c * N_ST + n] * factor;
}

// ---------------- pass1: v = u.B_d (bf16-packed to v_out) + chunk carry e ----------------
// thread (tg=tid>>6, ns=tid&63): owns t = tg*32..+32, n = ns*4..+4
__global__ __launch_bounds__(256, 1) void k_pass1v(const float* __restrict__ u,
                                                   const float* __restrict__ ws,
                                                   float* __restrict__ e_out,
                                                   unsigned int* __restrict__ v_out,
                                                   int b_off) {
    const int j  = blockIdx.x;
    const int bb = blockIdx.y;          // 0..7 within phase
    const int b  = bb + b_off;          // global batch
    const int tid = threadIdx.x;
    const int tg = tid >> 6;
    const int n0 = (tid & 63) * 4;

    __shared__ float u_lds[64 * 132];    // 33.8 KB  [c][t], stride 132
    __shared__ float part[4 * 256];      //  4 KB

    {   // stage u chunk [64c][128t], coalesced 128B runs per c
        const float* ub = u + (size_t)b * CIN * T_LEN + j * CHUNK;
#pragma unroll
        for (int p = 0; p < 2; ++p) {
            int c = p * 32 + (tid >> 3), k = tid & 7;
#pragma unroll
            for (int i = 0; i < 4; ++i)
                *(float4*)&u_lds[c * 132 + k * 16 + i * 4] =
                    *(const float4*)&ub[(size_t)c * T_LEN + k * 16 + i * 4];
        }
    }
    __syncthreads();

    float4 acc[32];                      // acc[i] = v[t=tg*32+i][n0..n0+4)
#pragma unroll
    for (int i = 0; i < 32; ++i) acc[i] = make_float4(0.f, 0.f, 0.f, 0.f);

    const float* Bd = ws + WS_BD;        // read direct from L2 (contiguous 1KB/wave/c)
#pragma unroll 2
    for (int c = 0; c < 64; ++c) {
        float4 bd4 = *(const float4*)&Bd[c * N_ST + n0];
        const float* ur = &u_lds[c * 132 + tg * 32];
#pragma unroll
        for (int q = 0; q < 8; ++q) {
            float4 uq = *(const float4*)&ur[q * 4];   // wave-broadcast
            FMA4(acc[q * 4 + 0], uq.x, bd4);
            FMA4(acc[q * 4 + 1], uq.y, bd4);
            FMA4(acc[q * 4 + 2], uq.z, bd4);
            FMA4(acc[q * 4 + 3], uq.w, bd4);
        }
    }

    // ---- chunk carry: p = sum_i A^(31-i) v[i]; combine 4 t-slices with A^32 ----
    {
        float4 a4 = *(const float4*)&ws[WS_AD + n0];
        float4 p = make_float4(0.f, 0.f, 0.f, 0.f);
#pragma unroll
        for (int i = 0; i < 32; ++i) {
            p.x = fmaf(p.x, a4.x, acc[i].x);
            p.y = fmaf(p.y, a4.y, acc[i].y);
            p.z = fmaf(p.z, a4.z, acc[i].z);
            p.w = fmaf(p.w, a4.w, acc[i].w);
        }
        *(float4*)&part[tg * 256 + n0] = p;
    }
    __syncthreads();
    if (tg == 0) {
        float4 A32 = *(const float4*)&ws[WS_A32 + n0];
        float4 e  = *(const float4*)&part[0 * 256 + n0];
        float4 p1 = *(const float4*)&part[1 * 256 + n0];
        float4 p2 = *(const float4*)&part[2 * 256 + n0];
        float4 p3 = *(const float4*)&part[3 * 256 + n0];
        e.x = fmaf(e.x, A32.x, p1.x); e.y = fmaf(e.y, A32.y, p1.y);
        e.z = fmaf(e.z, A32.z, p1.z); e.w = fmaf(e.w, A32.w, p1.w);
        e.x = fmaf(e.x, A32.x, p2.x); e.y = fmaf(e.y, A32.y, p2.y);
        e.z = fmaf(e.z, A32.z, p2.z); e.w = fmaf(e.w, A32.w, p2.w);
        e.x = fmaf(e.x, A32.x, p3.x); e.y = fmaf(e.y, A32.y, p3.y);
        e.z = fmaf(e.z, A32.z, p3.z); e.w = fmaf(e.w, A32.w, p3.w);
        *(float4*)&e_out[((size_t)j * B_SZ + b) * N_ST + n0] = e;
    }

    // ---- store v as bf16 pairs: v[bb][t2][n] uint, coalesced ----
    {
        size_t base = (((size_t)bb * 4096) + (size_t)j * 64 + tg * 16) * 256 + n0;
#pragma unroll
        for (int m = 0; m < 16; ++m) {
            uint4 w;
            w.x = pack2(acc[2 * m].x, acc[2 * m + 1].x);
            w.y = pack2(acc[2 * m].y, acc[2 * m + 1].y);
            w.z = pack2(acc[2 * m].z, acc[2 * m + 1].z);
            w.w = pack2(acc[2 * m].w, acc[2 * m + 1].w);
            *(uint4*)&v_out[base + (size_t)m * 256] = w;
        }
    }
}

// ---------------- pass2: chunk-prefix combine, e -> sinit in place ----------------
__global__ __launch_bounds__(256) void k_pass2(float* __restrict__ ws, int b_off) {
    const int b = blockIdx.x + b_off;
    const int n = threadIdx.x;
    const float AL = ws[WS_AL + n];
    float* es = ws + WS_ES;
    float ev[NCHUNK];
#pragma unroll
    for (int j = 0; j < NCHUNK; ++j)     // all loads issued up-front (independent)
        ev[j] = es[((size_t)j * B_SZ + b) * N_ST + n];
    float s = 0.f;
#pragma unroll
    for (int j = 0; j < NCHUNK; ++j) {
        es[((size_t)j * B_SZ + b) * N_ST + n] = s;   // sinit: state BEFORE chunk j
        s = s * AL + ev[j];
    }
}

// ---------------- pass3m: scan + MFMA projection (S.C) + LN + SiLU ----------------
// GEMM per block: y[128t][64o] = S[128t][256n] . C[256n][64o], bf16 MFMA 16x16x32.
// A-frag LDS Af[kt8][tt8][slot64][j8] bf16; scan thread n deposits its column with
// XOR swizzle slot = lgrp*16 + (t15 ^ g), g = (lgrp<<1)^(kt&1)  -> conflict-free b16
// writes AND b128 frag reads (read uses the same g => bijective, verified algebra).
// B-frag LDS Bf[kt8][ot4][lane64][j8] bf16 staged from C once (layout-native).
// D mapping (m89): col = lane&15 (o), row = (lane>>4)*4 + reg (t).
__global__ __launch_bounds__(256, 1) void k_pass3m(const float* __restrict__ C,
                                                   const float* __restrict__ ln_w,
                                                   const float* __restrict__ ln_b,
                                                   const float* __restrict__ ws,
                                                   const unsigned int* __restrict__ v_in,
                                                   float* __restrict__ y_out,
                                                   int b_off) {
    const int j  = blockIdx.x;
    const int bb = blockIdx.y;
    const int b  = bb + b_off;
    const int tid = threadIdx.x;

    __shared__ unsigned short Af[8 * 8 * 64 * 8];   // 64 KB
    __shared__ unsigned short Bf[8 * 4 * 64 * 8];   // 32 KB  => 96 KB total

    const int wv   = tid >> 6;       // wave 0..3 -> ttiles {2wv, 2wv+1}, stages ot=wv
    const int lane = tid & 63;
    const int lgrp = lane >> 4;      // 0..3
    const int r    = lane & 15;

    // ---- stage C -> B fragments (bf16). slot (kt=ii, ot=wv, lane). ----
#pragma unroll 2
    for (int ii = 0; ii < 8; ++ii) {
        const float* src = C + (size_t)(ii * 32 + lgrp * 8) * OCH + wv * 16 + r;
        float c0 = src[0*OCH], c1 = src[1*OCH], c2 = src[2*OCH], c3 = src[3*OCH];
        float c4 = src[4*OCH], c5 = src[5*OCH], c6 = src[6*OCH], c7 = src[7*OCH];
        uint4 wq;
        wq.x = pack2(c0, c1); wq.y = pack2(c2, c3);
        wq.z = pack2(c4, c5); wq.w = pack2(c6, c7);
        *(uint4*)&Bf[((ii * 4 + wv) * 64 + lane) * 8] = wq;
    }

    // ---- scan: thread = n, full 128-t chain; deposit bf16 into A-frag layout ----
    {
        const int n = tid;
        const float A = ws[WS_AD + n];
        float s = ws[WS_ES + ((size_t)j * B_SZ + b) * N_ST + n];
        size_t vb = (((size_t)bb * 4096) + (size_t)j * 64) * 256 + n;
        unsigned int vv[64];
#pragma unroll
        for (int i = 0; i < 64; ++i) vv[i] = v_in[vb + (size_t)i * 256];
        const int kt = n >> 5, lg = (n >> 3) & 3, jj = n & 7;
        const int g8 = ((lg << 1) ^ (kt & 1)) * 8;
        const int rowbase = kt * 4096 + lg * 128 + jj;
#pragma unroll
        for (int cu = 0; cu < 16; ++cu) {
            const int cb = rowbase + (cu >> 1) * 512 + (cu & 1) * 64;
#pragma unroll
            for (int h = 0; h < 4; ++h) {
                unsigned int w = vv[cu * 4 + h];
                s = fmaf(s, A, bf_lo(w));
                Af[cb + (((2 * h    ) * 8) ^ g8)] = (unsigned short)(rne16(s) >> 16);
                s = fmaf(s, A, bf_hi(w));
                Af[cb + (((2 * h + 1) * 8) ^ g8)] = (unsigned short)(rne16(s) >> 16);
            }
        }
    }
    __syncthreads();

    // ---- MFMA: wave wv computes ttiles {2wv,2wv+1} x 4 otiles over 8 ktiles ----
    f4v a00 = {0.f,0.f,0.f,0.f}, a01 = a00, a02 = a00, a03 = a00;
    f4v a10 = a00, a11 = a00, a12 = a00, a13 = a00;
    const int tt0 = 2 * wv, tt1 = 2 * wv + 1;
#pragma unroll
    for (int kt = 0; kt < 8; ++kt) {
        const int g8 = ((lgrp << 1) ^ (kt & 1)) * 8;
        const int ao = lgrp * 128 + ((r * 8) ^ g8);
        s8v fa0 = *(const s8v*)&Af[(kt * 8 + tt0) * 512 + ao];
        s8v fa1 = *(const s8v*)&Af[(kt * 8 + tt1) * 512 + ao];
        s8v fb0 = *(const s8v*)&Bf[(kt * 4 + 0) * 512 + lane * 8];
        s8v fb1 = *(const s8v*)&Bf[(kt * 4 + 1) * 512 + lane * 8];
        s8v fb2 = *(const s8v*)&Bf[(kt * 4 + 2) * 512 + lane * 8];
        s8v fb3 = *(const s8v*)&Bf[(kt * 4 + 3) * 512 + lane * 8];
        a00 = __builtin_amdgcn_mfma_f32_16x16x32_bf16(fa0, fb0, a00, 0, 0, 0);
        a01 = __builtin_amdgcn_mfma_f32_16x16x32_bf16(fa0, fb1, a01, 0, 0, 0);
        a02 = __builtin_amdgcn_mfma_f32_16x16x32_bf16(fa0, fb2, a02, 0, 0, 0);
        a03 = __builtin_amdgcn_mfma_f32_16x16x32_bf16(fa0, fb3, a03, 0, 0, 0);
        a10 = __builtin_amdgcn_mfma_f32_16x16x32_bf16(fa1, fb0, a10, 0, 0, 0);
        a11 = __builtin_amdgcn_mfma_f32_16x16x32_bf16(fa1, fb1, a11, 0, 0, 0);
        a12 = __builtin_amdgcn_mfma_f32_16x16x32_bf16(fa1, fb2, a12, 0, 0, 0);
        a13 = __builtin_amdgcn_mfma_f32_16x16x32_bf16(fa1, fb3, a13, 0, 0, 0);
    }

    // ---- LayerNorm + SiLU + store. lane holds o = {r,16+r,32+r,48+r}, t = tt*16+lgrp*4+q ----
    const float lw0 = ln_w[r],      lw1 = ln_w[16 + r];
    const float lw2 = ln_w[32 + r], lw3 = ln_w[48 + r];
    const float lb0 = ln_b[r],      lb1 = ln_b[16 + r];
    const float lb2 = ln_b[32 + r], lb3 = ln_b[48 + r];

#define LNQ(V0, V1, V2, V3, TT, Q) {                                          \
    float s1 = (V0) + (V1) + (V2) + (V3);                                     \
    float s2 = (V0)*(V0) + (V1)*(V1) + (V2)*(V2) + (V3)*(V3);                 \
    s1 += __shfl_xor(s1, 1, 64);  s2 += __shfl_xor(s2, 1, 64);                \
    s1 += __shfl_xor(s1, 2, 64);  s2 += __shfl_xor(s2, 2, 64);                \
    s1 += __shfl_xor(s1, 4, 64);  s2 += __shfl_xor(s2, 4, 64);                \
    s1 += __shfl_xor(s1, 8, 64);  s2 += __shfl_xor(s2, 8, 64);                \
    float mu = s1 * (1.f / 64.f);                                             \
    float var = s2 * (1.f / 64.f) - mu * mu;                                  \
    float rs = rsqrtf(var + 1e-5f);                                           \
    int t = j * CHUNK + (TT) * 16 + lgrp * 4 + (Q);                           \
    float* yr = y_out + ((size_t)b * T_LEN + t) * OCH + r;                    \
    float yn;                                                                 \
    yn = ((V0) - mu) * rs * lw0 + lb0; yr[0]  = yn / (1.f + expf(-yn));       \
    yn = ((V1) - mu) * rs * lw1 + lb1; yr[16] = yn / (1.f + expf(-yn));       \
    yn = ((V2) - mu) * rs * lw2 + lb2; yr[32] = yn / (1.f + expf(-yn));       \
    yn = ((V3) - mu) * rs * lw3 + lb3; yr[48] = yn / (1.f + expf(-yn));       \
}
    {
        float4 d0 = *(float4*)&a00, d1 = *(float4*)&a01;
        float4 d2 = *(float4*)&a02, d3 = *(float4*)&a03;
        LNQ(d0.x, d1.x, d2.x, d3.x, tt0, 0)
        LNQ(d0.y, d1.y, d2.y, d3.y, tt0, 1)
        LNQ(d0.z, d1.z, d2.z, d3.z, tt0, 2)
        LNQ(d0.w, d1.w, d2.w, d3.w, tt0, 3)
    }
    {
        float4 d0 = *(float4*)&a10, d1 = *(float4*)&a11;
        float4 d2 = *(float4*)&a12, d3 = *(float4*)&a13;
        LNQ(d0.x, d1.x, d2.x, d3.x, tt1, 0)
        LNQ(d0.y, d1.y, d2.y, d3.y, tt1, 1)
        LNQ(d0.z, d1.z, d2.z, d3.z, tt1, 2)
        LNQ(d0.w, d1.w, d2.w, d3.w, tt1, 3)
    }
#undef LNQ
}

// ---------------- conv2: upsample (channel-mix) + pointwise conv, register-tiled GEMM ----
// out[b][o][2tau(+1)] = sum_c2 W[o][c2] * V[c2][tau] + cb[o]
//   V[2c][tau] = y[b][tau][c], V[2c+1][tau] = y[b][T/2+tau][c]
// Block: 128 taus. Thread (og=tid&7 -> 8 o's, tg=tid>>3 -> 4 taus): 3 b128 per 32 FMA.
__global__ __launch_bounds__(256, 1) void k_conv2(const float* __restrict__ y,
                                                  const float* __restrict__ conv_w,
                                                  const float* __restrict__ conv_b,
                                                  float* __restrict__ out) {
    const int tb = blockIdx.x;     // 32 tau-blocks
    const int b  = blockIdx.y;
    const int tid = threadIdx.x;

    __shared__ float V[128 * 128];   // 64 KB  V[c2][tau]
    __shared__ float WT[128 * 64];   // 32 KB  WT[c2][o]

    {   // stage WT transposed: conv_w[o][c2] -> WT[c2][o]
        int o = tid >> 2, kk = tid & 3;
        const float4* src = (const float4*)(conv_w + (size_t)o * 128 + kk * 32);
#pragma unroll
        for (int q = 0; q < 8; ++q) {
            float4 w4 = src[q];
            int c2 = kk * 32 + q * 4;
            WT[(c2 + 0) * 64 + o] = w4.x;
            WT[(c2 + 1) * 64 + o] = w4.y;
            WT[(c2 + 2) * 64 + o] = w4.z;
            WT[(c2 + 3) * 64 + o] = w4.w;
        }
    }
    const int tau0 = tb * 128;
    {   // stage V: lanes along tau -> conflict-free b32 writes; 4 waves cover full 64B rows
        int lt = tid & 63;           // tau within 64-group
        int cg = tid >> 6;           // wave id -> c4 offset
        const float* ybl = y + ((size_t)b * T_LEN + tau0) * OCH;
        const float* ybh = y + ((size_t)b * T_LEN + T_LEN / 2 + tau0) * OCH;
#pragma unroll
        for (int it = 0; it < 8; ++it) {
            int tau = (it & 1) * 64 + lt;
            int c4  = (it >> 1) * 4 + cg;          // 0..15
            float4 lo = *(const float4*)&ybl[(size_t)tau * OCH + c4 * 4];
            float4 hi = *(const float4*)&ybh[(size_t)tau * OCH + c4 * 4];
            int c2 = c4 * 8;
            V[(c2 + 0) * 128 + tau] = lo.x;
            V[(c2 + 1) * 128 + tau] = hi.x;
            V[(c2 + 2) * 128 + tau] = lo.y;
            V[(c2 + 3) * 128 + tau] = hi.y;
            V[(c2 + 4) * 128 + tau] = lo.z;
            V[(c2 + 5) * 128 + tau] = hi.z;
            V[(c2 + 6) * 128 + tau] = lo.w;
            V[(c2 + 7) * 128 + tau] = hi.w;
        }
    }
    __syncthreads();

    const int og = tid & 7;          // o = og*8..+8
    const int tg = tid >> 3;         // tau = tg*4..+4
    float4 a0[4], a1[4];
#pragma unroll
    for (int ti = 0; ti < 4; ++ti) {
        a0[ti] = make_float4(0.f, 0.f, 0.f, 0.f);
        a1[ti] = make_float4(0.f, 0.f, 0.f, 0.f);
    }

#pragma unroll 4
    for (int c2 = 0; c2 < 128; ++c2) {
        float4 v4 = *(const float4*)&V[c2 * 128 + tg * 4];        // 8-addr broadcast
        float4 w0 = *(const float4*)&WT[c2 * 64 + og * 8];        // consecutive 16B
        float4 w1 = *(const float4*)&WT[c2 * 64 + og * 8 + 4];
        FMA4(a0[0], v4.x, w0); FMA4(a1[0], v4.x, w1);
        FMA4(a0[1], v4.y, w0); FMA4(a1[1], v4.y, w1);
        FMA4(a0[2], v4.z, w0); FMA4(a1[2], v4.z, w1);
        FMA4(a0[3], v4.w, w0); FMA4(a1[3], v4.w, w1);
    }

    // epilogue: + bias, duplicate to (2tau, 2tau+1)
    float4 cb0 = *(const float4*)&conv_b[og * 8];
    float4 cb1 = *(const float4*)&conv_b[og * 8 + 4];
    float* ob = out + (size_t)b * OCH * T_LEN + (size_t)og * 8 * T_LEN;
#pragma unroll
    for (int ti = 0; ti < 4; ++ti) {
        int t2 = 2 * (tau0 + tg * 4 + ti);
        float r;
        float2 rr;
        r = a0[ti].x + cb0.x; rr.x = r; rr.y = r; *(float2*)&ob[0 * T_LEN + t2] = rr;
        r = a0[ti].y + cb0.y; rr.x = r; rr.y = r; *(float2*)&ob[1 * T_LEN + t2] = rr;
        r = a0[ti].z + cb0.z; rr.x = r; rr.y = r; *(float2*)&ob[2 * T_LEN + t2] = rr;
        r = a0[ti].w + cb0.w; rr.x = r; rr.y = r; *(float2*)&ob[3 * T_LEN + t2] = rr;
        r = a1[ti].x + cb1.x; rr.x = r; rr.y = r; *(float2*)&ob[4 * T_LEN + t2] = rr;
        r = a1[ti].y + cb1.y; rr.x = r; rr.y = r; *(float2*)&ob[5 * T_LEN + t2] = rr;
        r = a1[ti].z + cb1.z; rr.x = r; rr.y = r; *(float2*)&ob[6 * T_LEN + t2] = rr;
        r = a1[ti].w + cb1.w; rr.x = r; rr.y = r; *(float2*)&ob[7 * T_LEN + t2] = rr;
    }
}

extern "C" void kernel_launch(void* const* d_in, const int* in_sizes, int n_in,
                              void* d_out, int out_size, void* d_ws, size_t ws_size,
                              hipStream_t stream) {
    const float* u          = (const float*)d_in[0];
    const float* raw_lambda = (const float*)d_in[1];
    const float* B_c        = (const float*)d_in[2];
    const float* C          = (const float*)d_in[3];
    const float* ln_w       = (const float*)d_in[4];
    const float* ln_b       = (const float*)d_in[5];
    const float* conv_w     = (const float*)d_in[6];
    const float* conv_b     = (const float*)d_in[7];
    float* out = (float*)d_out;
    float* ws  = (float*)d_ws;
    (void)in_sizes; (void)n_in; (void)out_size; (void)ws_size;

    // v scratch (packed bf16 pairs) lives in d_out: 8 batches * 4096 * 256 uints
    // = 33.5 MB = exactly out_size. Two phases of 8 batches; v is fully dead
    // before k_conv2 finally overwrites d_out with the real output.
    unsigned int* v = (unsigned int*)d_out;

    k_prep<<<1, 256, 0, stream>>>(raw_lambda, B_c, ws);
    for (int phase = 0; phase < 2; ++phase) {
        int b_off = phase * 8;
        k_pass1v<<<dim3(NCHUNK, 8), 256, 0, stream>>>(u, ws, ws + WS_ES, v, b_off);
        k_pass2 <<<8, 256, 0, stream>>>(ws, b_off);
        k_pass3m<<<dim3(NCHUNK, 8), 256, 0, stream>>>(C, ln_w, ln_b, ws, v, ws + WS_Y, b_off);
    }
    k_conv2<<<dim3(T_LEN / 2 / 128, B_SZ), 256, 0, stream>>>(ws + WS_Y, conv_w, conv_b, out);
}